// Round 1
// baseline (2762.437 us; speedup 1.0000x reference)
//
#include <hip/hip_runtime.h>
#include <math.h>

#define HDIM 256
#define NLAYERS 6

__device__ __forceinline__ float silu_(float x){ return x * (1.f/(1.f+__expf(-x))); }

// ---------------- degree counting ----------------
__global__ void k_count(const int* __restrict__ src, const int* __restrict__ dst, int E,
                        int* __restrict__ cnt_out, int* __restrict__ cnt_in){
  int e = blockIdx.x*256 + threadIdx.x;
  if(e < E){
    atomicAdd(&cnt_out[src[e]], 1);
    atomicAdd(&cnt_in[dst[e]], 1);
  }
}

// ---------------- exclusive scan of cnt_in -> csr_off (single block) ----------------
__global__ __launch_bounds__(1024) void k_scan(const int* __restrict__ cnt_in,
                                               int* __restrict__ csr_off, int N){
  __shared__ int s[1024];
  int t = threadIdx.x;
  int chunk = (N + 1023) >> 10;
  int b0 = t * chunk;
  int loc = 0;
  for(int j=0;j<chunk;j++){ int i=b0+j; if(i<N) loc += cnt_in[i]; }
  s[t] = loc; __syncthreads();
  for(int off=1; off<1024; off<<=1){
    int v = (t>=off) ? s[t-off] : 0;
    __syncthreads();
    s[t] += v;
    __syncthreads();
  }
  int run = (t==0) ? 0 : s[t-1];
  for(int j=0;j<chunk;j++){
    int i=b0+j;
    if(i<N){ csr_off[i] = run; run += cnt_in[i]; }
  }
  if(t==1023) csr_off[N] = run;
}

// ---------------- norms + csr fill pointer ----------------
__global__ void k_prep(const int* __restrict__ cnt_out, const int* __restrict__ cnt_in,
                       const int* __restrict__ csr_off,
                       float* __restrict__ no, float* __restrict__ ni,
                       int* __restrict__ csr_pos, int N){
  int v = blockIdx.x*256 + threadIdx.x;
  if(v < N){
    no[v] = rsqrtf((float)max(cnt_out[v],1));
    ni[v] = rsqrtf((float)max(cnt_in[v],1));
    csr_pos[v] = csr_off[v];
  }
}

__global__ void k_fill(const int* __restrict__ src, const int* __restrict__ dst, int E,
                       int* __restrict__ csr_pos, int* __restrict__ csr_src,
                       int* __restrict__ csr_eid){
  int e = blockIdx.x*256 + threadIdx.x;
  if(e < E){
    int p = atomicAdd(&csr_pos[dst[e]], 1);
    csr_src[p] = src[e];
    csr_eid[p] = e;
  }
}

// ---------------- time embedding + MLP -> cond (one block per batch elem) ----------------
__global__ __launch_bounds__(256) void k_cond(const float* __restrict__ t,
        const float* __restrict__ w1, const float* __restrict__ b1,
        const float* __restrict__ w2, const float* __restrict__ b2,
        float* __restrict__ cond){
  __shared__ float emb[128];
  __shared__ float hid[256];
  int b = blockIdx.x, tid = threadIdx.x;
  float tv = t[b] * 1000.f;
  if(tid < 128){
    int k = tid & 63;
    float fr = expf(-logf(1000.f) * (float)k * (1.f/64.f));
    float a = tv * fr;
    emb[tid] = (tid < 64) ? sinf(a) : cosf(a);
  }
  __syncthreads();
  {
    float s = b1[tid];
    for(int k=0;k<128;k++) s += emb[k] * w1[k*HDIM + tid];
    hid[tid] = silu_(s);
  }
  __syncthreads();
  {
    float s = b2[tid];
    for(int k=0;k<256;k++) s += hid[k] * w2[k*HDIM + tid];
    cond[(size_t)b*HDIM + tid] = s;
  }
}

// ---------------- gb[i][b][512] = cond[b] @ film2_w[i] + film2_b[i] ----------------
// block: 4 batch rows x 3072 cols
__global__ __launch_bounds__(256) void k_gb(const float* __restrict__ cond,
        const float* __restrict__ fw, const float* __restrict__ fb,
        float* __restrict__ gb, int B){
  __shared__ float cs[4][256];
  int tid = threadIdx.x;
  int b0 = blockIdx.x * 4;
  for(int r=0;r<4;r++) cs[r][tid] = cond[(size_t)(b0+r)*HDIM + tid];
  __syncthreads();
  float acc[4][12];
  #pragma unroll
  for(int r=0;r<4;r++)
    #pragma unroll
    for(int m=0;m<12;m++) acc[r][m] = 0.f;
  int baseA[12];
  #pragma unroll
  for(int m=0;m<12;m++){
    int c = tid + 256*m;
    baseA[m] = (c>>9)*131072 + (c&511);   // (i*256)*512 + jj
  }
  for(int k=0;k<256;k++){
    float c0=cs[0][k], c1=cs[1][k], c2=cs[2][k], c3=cs[3][k];
    #pragma unroll
    for(int m=0;m<12;m++){
      float w = fw[baseA[m] + k*512];
      acc[0][m] += c0*w; acc[1][m] += c1*w; acc[2][m] += c2*w; acc[3][m] += c3*w;
    }
  }
  #pragma unroll
  for(int m=0;m<12;m++){
    int c = tid + 256*m;
    int i = c>>9, jj = c&511;
    float bb = fb[c];
    #pragma unroll
    for(int r=0;r<4;r++)
      gb[((size_t)i*B + (b0+r))*512 + jj] = acc[r][m] + bb;
  }
}

// ---------------- build stacked init weight [64][256] ----------------
__global__ void k_wcat(const float* __restrict__ in_w, const float* __restrict__ ew,
                       const float* __restrict__ eb, float* __restrict__ wcat){
  int idx = blockIdx.x*256 + threadIdx.x;   // 64*256
  int r = idx>>8, c = idx&255;
  float v = 0.f;
  if(r < 32) v = in_w[r*HDIM + c];
  else if(r < 48) v = ew[(r-32)*HDIM + c];
  else if(r == 48) v = eb[c];
  wcat[idx] = v;
}

// ---------------- init aggregation: A48[v][64] = [ax*ni | ae/deg | flag | 0...] ----------------
__global__ __launch_bounds__(256) void k_init_agg(const float* __restrict__ node_x,
    const float* __restrict__ edge_e,
    const int* __restrict__ csr_off, const int* __restrict__ csr_src, const int* __restrict__ csr_eid,
    const float* __restrict__ no, const float* __restrict__ ni, const int* __restrict__ cnt_in,
    float* __restrict__ A48, int N){
  int v = blockIdx.x*4 + (threadIdx.x>>6);
  if(v >= N) return;
  int lane = threadIdx.x & 63;
  int beg = csr_off[v], end = csr_off[v+1];
  float acc = 0.f;
  for(int p=beg; p<end; p++){
    int s = csr_src[p]; int e = csr_eid[p];
    if(lane < 32)      acc += node_x[(size_t)s*32 + lane] * no[s];
    else if(lane < 48) acc += edge_e[(size_t)e*16 + (lane-32)];
  }
  int ci = cnt_in[v];
  float out;
  if(lane < 32)      out = acc * ni[v];
  else if(lane < 48) out = acc * (1.f/(float)max(ci,1));
  else if(lane == 48) out = (ci>0) ? 1.f : 0.f;
  else out = 0.f;
  A48[(size_t)v*64 + lane] = out;
}

// ---------------- per-layer gather: agg[v] = ni[v] * sum_in h[src]*no[src] ----------------
__global__ __launch_bounds__(256) void k_gather(const float* __restrict__ h,
   const int* __restrict__ csr_off, const int* __restrict__ csr_src,
   const float* __restrict__ no, const float* __restrict__ ni,
   float* __restrict__ agg, int N){
  int v = blockIdx.x*4 + (threadIdx.x>>6);
  if(v >= N) return;
  int lane = threadIdx.x & 63;
  int beg = csr_off[v], end = csr_off[v+1];
  float4 acc = make_float4(0.f,0.f,0.f,0.f);
  for(int p=beg; p<end; p++){
    int s = csr_src[p];
    float w = no[s];
    float4 x = *(const float4*)&h[(size_t)s*HDIM + lane*4];
    acc.x += x.x*w; acc.y += x.y*w; acc.z += x.z*w; acc.w += x.w*w;
  }
  float sc = ni[v];
  acc.x*=sc; acc.y*=sc; acc.z*=sc; acc.w*=sc;
  *(float4*)&agg[(size_t)v*HDIM + lane*4] = acc;
}

// ---------------- tiled GEMM (64 rows x 256 cols) with fused epilogue ----------------
// LAYER=false: h = A@W + bias       (init, K=64)
// LAYER=true : h += silu(film(ln(A@W + bias)))   (K=256, in-place residual)
template<int K, bool LAYER>
__global__ __launch_bounds__(256) void k_gemm(
    const float* __restrict__ A, const float* __restrict__ W, const float* __restrict__ bias,
    const float* __restrict__ lng, const float* __restrict__ lnb,
    const float* __restrict__ gb, const int* __restrict__ n_index,
    float* __restrict__ h, int N){
  __shared__ float As[64][36];
  __shared__ float Ws[32][256];
  const int tid = threadIdx.x;
  const int rg = tid >> 4;      // 0..15 row group (4 rows each)
  const int cg = tid & 15;      // 0..15 col group
  const int row0 = blockIdx.x * 64;

  float4 acc[4][4];
  #pragma unroll
  for(int i=0;i<4;i++)
    #pragma unroll
    for(int m=0;m<4;m++) acc[i][m] = make_float4(0.f,0.f,0.f,0.f);

  const int ar = tid >> 2;          // 0..63
  const int ac = (tid & 3) * 8;     // 0,8,16,24
  const int wr = tid >> 3;          // 0..31
  const int wc = (tid & 7) * 32;    // 0..224

  for(int kk=0; kk<K; kk+=32){
    {
      int gr = row0 + ar;
      float4 v0 = make_float4(0.f,0.f,0.f,0.f), v1 = v0;
      if(gr < N){
        v0 = *(const float4*)&A[(size_t)gr*K + kk + ac];
        v1 = *(const float4*)&A[(size_t)gr*K + kk + ac + 4];
      }
      *(float4*)&As[ar][ac]   = v0;
      *(float4*)&As[ar][ac+4] = v1;
    }
    #pragma unroll
    for(int u=0;u<8;u++)
      *(float4*)&Ws[wr][wc + u*4] = *(const float4*)&W[(size_t)(kk+wr)*HDIM + wc + u*4];
    __syncthreads();
    #pragma unroll 8
    for(int k=0;k<32;k++){
      float a0 = As[rg*4+0][k];
      float a1 = As[rg*4+1][k];
      float a2 = As[rg*4+2][k];
      float a3 = As[rg*4+3][k];
      #pragma unroll
      for(int m=0;m<4;m++){
        float4 w = *(const float4*)&Ws[k][cg*4 + m*64];
        acc[0][m].x += a0*w.x; acc[0][m].y += a0*w.y; acc[0][m].z += a0*w.z; acc[0][m].w += a0*w.w;
        acc[1][m].x += a1*w.x; acc[1][m].y += a1*w.y; acc[1][m].z += a1*w.z; acc[1][m].w += a1*w.w;
        acc[2][m].x += a2*w.x; acc[2][m].y += a2*w.y; acc[2][m].z += a2*w.z; acc[2][m].w += a2*w.w;
        acc[3][m].x += a3*w.x; acc[3][m].y += a3*w.y; acc[3][m].z += a3*w.z; acc[3][m].w += a3*w.w;
      }
    }
    __syncthreads();
  }

  const int c0 = cg * 4;
  #pragma unroll
  for(int i=0;i<4;i++){
    const int gr = row0 + rg*4 + i;
    const bool ok = gr < N;
    if(!LAYER){
      #pragma unroll
      for(int m=0;m<4;m++){
        const int c = c0 + m*64;
        float4 b4 = *(const float4*)&bias[c];
        float4 o = make_float4(acc[i][m].x+b4.x, acc[i][m].y+b4.y,
                               acc[i][m].z+b4.z, acc[i][m].w+b4.w);
        if(ok) *(float4*)&h[(size_t)gr*HDIM + c] = o;
      }
    } else {
      float z[16];
      float s = 0.f;
      #pragma unroll
      for(int m=0;m<4;m++){
        const int c = c0 + m*64;
        float4 b4 = *(const float4*)&bias[c];
        z[m*4+0] = acc[i][m].x + b4.x;
        z[m*4+1] = acc[i][m].y + b4.y;
        z[m*4+2] = acc[i][m].z + b4.z;
        z[m*4+3] = acc[i][m].w + b4.w;
        s += z[m*4+0]+z[m*4+1]+z[m*4+2]+z[m*4+3];
      }
      #pragma unroll
      for(int off=1; off<16; off<<=1) s += __shfl_xor(s, off, 64);
      const float mu = s * (1.f/256.f);
      float ss = 0.f;
      #pragma unroll
      for(int j=0;j<16;j++){ float d = z[j]-mu; ss += d*d; }
      #pragma unroll
      for(int off=1; off<16; off<<=1) ss += __shfl_xor(ss, off, 64);
      const float rs = rsqrtf(ss*(1.f/256.f) + 1e-5f);
      const int bidx = ok ? n_index[gr] : 0;
      const float* grow = gb + (size_t)bidx*512;
      #pragma unroll
      for(int m=0;m<4;m++){
        const int c = c0 + m*64;
        float4 g4  = *(const float4*)&lng[c];
        float4 lb4 = *(const float4*)&lnb[c];
        float4 gam = *(const float4*)&grow[c];
        float4 bet = *(const float4*)&grow[256+c];
        float4 hv = make_float4(0.f,0.f,0.f,0.f);
        if(ok) hv = *(const float4*)&h[(size_t)gr*HDIM + c];
        float4 o;
        { float zz=(z[m*4+0]-mu)*rs*g4.x+lb4.x; zz=zz*(1.f+gam.x)+bet.x; zz=silu_(zz); o.x=zz+hv.x; }
        { float zz=(z[m*4+1]-mu)*rs*g4.y+lb4.y; zz=zz*(1.f+gam.y)+bet.y; zz=silu_(zz); o.y=zz+hv.y; }
        { float zz=(z[m*4+2]-mu)*rs*g4.z+lb4.z; zz=zz*(1.f+gam.z)+bet.z; zz=silu_(zz); o.z=zz+hv.z; }
        { float zz=(z[m*4+3]-mu)*rs*g4.w+lb4.w; zz=zz*(1.f+gam.w)+bet.w; zz=silu_(zz); o.w=zz+hv.w; }
        if(ok) *(float4*)&h[(size_t)gr*HDIM + c] = o;
      }
    }
  }
}

// ---------------- head: per-node dot with head_w, atomic into per-graph sums ----------------
__global__ __launch_bounds__(256) void k_head(const float* __restrict__ h,
    const float* __restrict__ hw, const int* __restrict__ n_index,
    float* __restrict__ gsum, int* __restrict__ gcnt, int N){
  int v = blockIdx.x*4 + (threadIdx.x>>6);
  if(v >= N) return;
  int lane = threadIdx.x & 63;
  float4 x = *(const float4*)&h[(size_t)v*HDIM + lane*4];
  float4 w = *(const float4*)&hw[lane*4];
  float s = x.x*w.x + x.y*w.y + x.z*w.z + x.w*w.w;
  #pragma unroll
  for(int off=32; off; off>>=1) s += __shfl_xor(s, off, 64);
  if(lane == 0){
    int b = n_index[v];
    atomicAdd(&gsum[b], s);
    atomicAdd(&gcnt[b], 1);
  }
}

__global__ void k_final(const float* __restrict__ gsum, const int* __restrict__ gcnt,
                        const float* __restrict__ hb, float* __restrict__ out, int B){
  int b = blockIdx.x*256 + threadIdx.x;
  if(b < B) out[b] = gsum[b] / (float)max(gcnt[b],1) + hb[0];
}

extern "C" void kernel_launch(void* const* d_in, const int* in_sizes, int n_in,
                              void* d_out, int out_size, void* d_ws, size_t ws_size,
                              hipStream_t stream){
  const float* node_x   = (const float*)d_in[0];
  const float* edge_e   = (const float*)d_in[1];
  const float* t        = (const float*)d_in[2];
  const int*   n_index  = (const int*)d_in[3];
  const int*   src      = (const int*)d_in[4];
  const int*   dst      = (const int*)d_in[5];
  const float* in_conv_w= (const float*)d_in[6];
  const float* in_conv_b= (const float*)d_in[7];
  const float* edge_w   = (const float*)d_in[8];
  const float* edge_b   = (const float*)d_in[9];
  const float* t_w1     = (const float*)d_in[10];
  const float* t_b1     = (const float*)d_in[11];
  const float* t_w2     = (const float*)d_in[12];
  const float* t_b2     = (const float*)d_in[13];
  const float* conv2_w  = (const float*)d_in[16];
  const float* conv2_b  = (const float*)d_in[17];
  const float* ln2_g    = (const float*)d_in[20];
  const float* ln2_b    = (const float*)d_in[21];
  const float* film2_w  = (const float*)d_in[24];
  const float* film2_b  = (const float*)d_in[25];
  const float* head_w   = (const float*)d_in[26];
  const float* head_b   = (const float*)d_in[27];

  const int N = in_sizes[3];
  const int E = in_sizes[4];
  const int B = in_sizes[2];

  char* w = (char*)d_ws;
  auto alloc = [&](size_t bytes)->char*{
    char* p = w; w += (bytes + 255) & ~(size_t)255; return p;
  };
  int*   cnt_out = (int*)  alloc((size_t)N*4);
  int*   cnt_in  = (int*)  alloc((size_t)N*4);
  float* no      = (float*)alloc((size_t)N*4);
  float* ni      = (float*)alloc((size_t)N*4);
  int*   csr_off = (int*)  alloc((size_t)(N+1)*4);
  int*   csr_pos = (int*)  alloc((size_t)N*4);
  int*   csr_src = (int*)  alloc((size_t)E*4);
  int*   csr_eid = (int*)  alloc((size_t)E*4);
  float* cond    = (float*)alloc((size_t)B*HDIM*4);
  float* gb      = (float*)alloc((size_t)NLAYERS*B*512*4);
  float* gsum    = (float*)alloc((size_t)B*4);
  int*   gcnt    = (int*)  alloc((size_t)B*4);
  float* h       = (float*)alloc((size_t)N*HDIM*4);
  float* agg     = (float*)alloc((size_t)N*HDIM*4);
  float* wcat    = (float*)alloc((size_t)64*HDIM*4);
  float* A48     = agg;   // init-stage A (N x 64) reuses agg region

  hipMemsetAsync(cnt_out, 0, (size_t)N*4, stream);
  hipMemsetAsync(cnt_in,  0, (size_t)N*4, stream);
  hipMemsetAsync(gsum,    0, (size_t)B*4, stream);
  hipMemsetAsync(gcnt,    0, (size_t)B*4, stream);

  int gE = (E+255)/256, gN = (N+255)/256;
  k_count<<<gE,256,0,stream>>>(src, dst, E, cnt_out, cnt_in);
  k_scan<<<1,1024,0,stream>>>(cnt_in, csr_off, N);
  k_prep<<<gN,256,0,stream>>>(cnt_out, cnt_in, csr_off, no, ni, csr_pos, N);
  k_fill<<<gE,256,0,stream>>>(src, dst, E, csr_pos, csr_src, csr_eid);

  k_cond<<<B,256,0,stream>>>(t, t_w1, t_b1, t_w2, t_b2, cond);
  k_gb<<<B/4,256,0,stream>>>(cond, film2_w, film2_b, gb, B);

  k_wcat<<<64,256,0,stream>>>(in_conv_w, edge_w, edge_b, wcat);
  k_init_agg<<<(N+3)/4,256,0,stream>>>(node_x, edge_e, csr_off, csr_src, csr_eid,
                                       no, ni, cnt_in, A48, N);
  int gT = (N+63)/64;
  k_gemm<64,false><<<gT,256,0,stream>>>(A48, wcat, in_conv_b,
                                        nullptr, nullptr, nullptr, nullptr, h, N);

  for(int i=0;i<NLAYERS;i++){
    k_gather<<<(N+3)/4,256,0,stream>>>(h, csr_off, csr_src, no, ni, agg, N);
    k_gemm<256,true><<<gT,256,0,stream>>>(agg, conv2_w + (size_t)i*HDIM*HDIM,
                                          conv2_b + (size_t)i*HDIM,
                                          ln2_g + (size_t)i*HDIM, ln2_b + (size_t)i*HDIM,
                                          gb + (size_t)i*B*512, n_index, h, N);
  }

  k_head<<<(N+3)/4,256,0,stream>>>(h, head_w, n_index, gsum, gcnt, N);
  k_final<<<(B+255)/256,256,0,stream>>>(gsum, gcnt, head_b, (float*)d_out, B);
}

// Round 2
// 2291.155 us; speedup vs baseline: 1.2057x; 1.2057x over previous
//
#include <hip/hip_runtime.h>
#include <math.h>

#define HDIM 256
#define NLAYERS 6

typedef __attribute__((ext_vector_type(8))) short short8v;
typedef __attribute__((ext_vector_type(16))) float f32x16;

__device__ __forceinline__ float silu_(float x){ return x * (1.f/(1.f+__expf(-x))); }

__device__ __forceinline__ unsigned short f2bf(float f){
  unsigned u = __float_as_uint(f);
  u += 0x7FFF + ((u>>16)&1);
  return (unsigned short)(u>>16);
}
__device__ __forceinline__ float bf2f(unsigned short b){ return __uint_as_float(((unsigned)b)<<16); }

// ---------------- degree counting ----------------
__global__ void k_count(const int* __restrict__ src, const int* __restrict__ dst, int E,
                        int* __restrict__ cnt_out, int* __restrict__ cnt_in){
  int e = blockIdx.x*256 + threadIdx.x;
  if(e < E){
    atomicAdd(&cnt_out[src[e]], 1);
    atomicAdd(&cnt_in[dst[e]], 1);
  }
}

// ---------------- exclusive scan of cnt_in -> csr_off (single block) ----------------
__global__ __launch_bounds__(1024) void k_scan(const int* __restrict__ cnt_in,
                                               int* __restrict__ csr_off, int N){
  __shared__ int s[1024];
  int t = threadIdx.x;
  int chunk = (N + 1023) >> 10;
  int b0 = t * chunk;
  int loc = 0;
  for(int j=0;j<chunk;j++){ int i=b0+j; if(i<N) loc += cnt_in[i]; }
  s[t] = loc; __syncthreads();
  for(int off=1; off<1024; off<<=1){
    int v = (t>=off) ? s[t-off] : 0;
    __syncthreads();
    s[t] += v;
    __syncthreads();
  }
  int run = (t==0) ? 0 : s[t-1];
  for(int j=0;j<chunk;j++){
    int i=b0+j;
    if(i<N){ csr_off[i] = run; run += cnt_in[i]; }
  }
  if(t==1023) csr_off[N] = run;
}

// ---------------- norms + csr fill pointer ----------------
__global__ void k_prep(const int* __restrict__ cnt_out, const int* __restrict__ cnt_in,
                       const int* __restrict__ csr_off,
                       float* __restrict__ no, float* __restrict__ ni,
                       int* __restrict__ csr_pos, int N){
  int v = blockIdx.x*256 + threadIdx.x;
  if(v < N){
    no[v] = rsqrtf((float)max(cnt_out[v],1));
    ni[v] = rsqrtf((float)max(cnt_in[v],1));
    csr_pos[v] = csr_off[v];
  }
}

__global__ void k_fill(const int* __restrict__ src, const int* __restrict__ dst, int E,
                       int* __restrict__ csr_pos, int* __restrict__ csr_src,
                       int* __restrict__ csr_eid){
  int e = blockIdx.x*256 + threadIdx.x;
  if(e < E){
    int p = atomicAdd(&csr_pos[dst[e]], 1);
    csr_src[p] = src[e];
    csr_eid[p] = e;
  }
}

// ---------------- time embedding + MLP -> cond ----------------
__global__ __launch_bounds__(256) void k_cond(const float* __restrict__ t,
        const float* __restrict__ w1, const float* __restrict__ b1,
        const float* __restrict__ w2, const float* __restrict__ b2,
        float* __restrict__ cond){
  __shared__ float emb[128];
  __shared__ float hid[256];
  int b = blockIdx.x, tid = threadIdx.x;
  float tv = t[b] * 1000.f;
  if(tid < 128){
    int k = tid & 63;
    float fr = expf(-logf(1000.f) * (float)k * (1.f/64.f));
    float a = tv * fr;
    emb[tid] = (tid < 64) ? sinf(a) : cosf(a);
  }
  __syncthreads();
  {
    float s = b1[tid];
    for(int k=0;k<128;k++) s += emb[k] * w1[k*HDIM + tid];
    hid[tid] = silu_(s);
  }
  __syncthreads();
  {
    float s = b2[tid];
    for(int k=0;k<256;k++) s += hid[k] * w2[k*HDIM + tid];
    cond[(size_t)b*HDIM + tid] = s;
  }
}

// ---------------- generic f32 tiled GEMM: 64 rows x 256 cols per block ----------------
// mode==1: gb-chunk mode, blockIdx.y selects (i,half) of film2_w / film2_b / gbX
template<int K>
__global__ __launch_bounds__(256) void k_gemm_f32(
    const float* __restrict__ A, int lda,
    const float* __restrict__ W, int ldw,
    const float* __restrict__ bias,
    float* __restrict__ out, int ldo, int M, int mode){
  if(mode == 1){
    int c = blockIdx.y;
    W    += (size_t)(c>>1)*131072 + (size_t)(c&1)*256;
    bias += (size_t)(c>>1)*512 + (size_t)(c&1)*256;
    out  += (size_t)c*1024*256;
  }
  __shared__ float As[64][36];
  __shared__ float Ws[32][256];
  const int tid = threadIdx.x;
  const int rg = tid >> 4;
  const int cg = tid & 15;
  const int row0 = blockIdx.x * 64;

  float4 acc[4][4];
  #pragma unroll
  for(int i=0;i<4;i++)
    #pragma unroll
    for(int m=0;m<4;m++) acc[i][m] = make_float4(0.f,0.f,0.f,0.f);

  const int ar = tid >> 2;
  const int ac = (tid & 3) * 8;
  const int wr = tid >> 3;
  const int wc = (tid & 7) * 32;

  for(int kk=0; kk<K; kk+=32){
    {
      int gr = row0 + ar;
      float4 v0 = make_float4(0.f,0.f,0.f,0.f), v1 = v0;
      if(gr < M){
        v0 = *(const float4*)&A[(size_t)gr*lda + kk + ac];
        v1 = *(const float4*)&A[(size_t)gr*lda + kk + ac + 4];
      }
      *(float4*)&As[ar][ac]   = v0;
      *(float4*)&As[ar][ac+4] = v1;
    }
    #pragma unroll
    for(int u=0;u<8;u++)
      *(float4*)&Ws[wr][wc + u*4] = *(const float4*)&W[(size_t)(kk+wr)*ldw + wc + u*4];
    __syncthreads();
    #pragma unroll 8
    for(int k=0;k<32;k++){
      float a0 = As[rg*4+0][k];
      float a1 = As[rg*4+1][k];
      float a2 = As[rg*4+2][k];
      float a3 = As[rg*4+3][k];
      #pragma unroll
      for(int m=0;m<4;m++){
        float4 w = *(const float4*)&Ws[k][cg*4 + m*64];
        acc[0][m].x += a0*w.x; acc[0][m].y += a0*w.y; acc[0][m].z += a0*w.z; acc[0][m].w += a0*w.w;
        acc[1][m].x += a1*w.x; acc[1][m].y += a1*w.y; acc[1][m].z += a1*w.z; acc[1][m].w += a1*w.w;
        acc[2][m].x += a2*w.x; acc[2][m].y += a2*w.y; acc[2][m].z += a2*w.z; acc[2][m].w += a2*w.w;
        acc[3][m].x += a3*w.x; acc[3][m].y += a3*w.y; acc[3][m].z += a3*w.z; acc[3][m].w += a3*w.w;
      }
    }
    __syncthreads();
  }

  const int c0 = cg * 4;
  #pragma unroll
  for(int i=0;i<4;i++){
    const int gr = row0 + rg*4 + i;
    if(gr >= M) continue;
    #pragma unroll
    for(int m=0;m<4;m++){
      const int c = c0 + m*64;
      float4 b4 = *(const float4*)&bias[c];
      float4 o = make_float4(acc[i][m].x+b4.x, acc[i][m].y+b4.y,
                             acc[i][m].z+b4.z, acc[i][m].w+b4.w);
      *(float4*)&out[(size_t)gr*ldo + c] = o;
    }
  }
}

// ---------------- build stacked init weight [64][256] ----------------
__global__ void k_wcat(const float* __restrict__ in_w, const float* __restrict__ ew,
                       const float* __restrict__ eb, float* __restrict__ wcat){
  int idx = blockIdx.x*256 + threadIdx.x;
  int r = idx>>8, c = idx&255;
  float v = 0.f;
  if(r < 32) v = in_w[r*HDIM + c];
  else if(r < 48) v = ew[(r-32)*HDIM + c];
  else if(r == 48) v = eb[c];
  wcat[idx] = v;
}

// ---------------- prepack conv2_w: transpose + bf16 hi/lo split ----------------
__global__ void k_w2b(const float* __restrict__ W, unsigned short* __restrict__ hi_,
                      unsigned short* __restrict__ lo_){
  int idx = blockIdx.x*256 + threadIdx.x;   // 6*65536
  int i = idx >> 16, r = idx & 65535;
  int n = r >> 8, k = r & 255;
  float v = W[((size_t)i*256 + k)*256 + n];
  unsigned short h = f2bf(v);
  float lo = v - bf2f(h);
  hi_[((size_t)i*256 + n)*256 + k] = h;
  lo_[((size_t)i*256 + n)*256 + k] = f2bf(lo);
}

// ---------------- init aggregation ----------------
__global__ __launch_bounds__(256) void k_init_agg(const float* __restrict__ node_x,
    const float* __restrict__ edge_e,
    const int* __restrict__ csr_off, const int* __restrict__ csr_src, const int* __restrict__ csr_eid,
    const float* __restrict__ no, const float* __restrict__ ni, const int* __restrict__ cnt_in,
    float* __restrict__ A48, int N){
  int v = blockIdx.x*4 + (threadIdx.x>>6);
  if(v >= N) return;
  int lane = threadIdx.x & 63;
  int beg = csr_off[v], end = csr_off[v+1];
  float acc = 0.f;
  for(int p=beg; p<end; p++){
    int s = csr_src[p]; int e = csr_eid[p];
    if(lane < 32)      acc += node_x[(size_t)s*32 + lane] * no[s];
    else if(lane < 48) acc += edge_e[(size_t)e*16 + (lane-32)];
  }
  int ci = cnt_in[v];
  float out;
  if(lane < 32)      out = acc * ni[v];
  else if(lane < 48) out = acc * (1.f/(float)max(ci,1));
  else if(lane == 48) out = (ci>0) ? 1.f : 0.f;
  else out = 0.f;
  A48[(size_t)v*64 + lane] = out;
}

// ---------------- per-layer gather -> bf16 hi/lo ----------------
__global__ __launch_bounds__(256) void k_gather_bf(const float* __restrict__ h,
   const int* __restrict__ csr_off, const int* __restrict__ csr_src,
   const float* __restrict__ no, const float* __restrict__ ni,
   unsigned short* __restrict__ ahi, unsigned short* __restrict__ alo, int N, int Npad){
  int v = blockIdx.x*4 + (threadIdx.x>>6);
  if(v >= Npad) return;
  int lane = threadIdx.x & 63;
  float4 acc = make_float4(0.f,0.f,0.f,0.f);
  if(v < N){
    int beg = csr_off[v], end = csr_off[v+1];
    for(int p=beg; p<end; p++){
      int s = csr_src[p];
      float w = no[s];
      float4 x = *(const float4*)&h[(size_t)s*HDIM + lane*4];
      acc.x += x.x*w; acc.y += x.y*w; acc.z += x.z*w; acc.w += x.w*w;
    }
    float sc = ni[v];
    acc.x*=sc; acc.y*=sc; acc.z*=sc; acc.w*=sc;
  }
  unsigned short h0 = f2bf(acc.x), h1 = f2bf(acc.y), h2 = f2bf(acc.z), h3 = f2bf(acc.w);
  ushort4 hv = make_ushort4(h0,h1,h2,h3);
  ushort4 lv = make_ushort4(f2bf(acc.x - bf2f(h0)), f2bf(acc.y - bf2f(h1)),
                            f2bf(acc.z - bf2f(h2)), f2bf(acc.w - bf2f(h3)));
  *(ushort4*)&ahi[(size_t)v*HDIM + lane*4] = hv;
  *(ushort4*)&alo[(size_t)v*HDIM + lane*4] = lv;
}

// ---------------- layer GEMM: bf16 MFMA 3-term hi/lo + fused LN/FiLM/SiLU/residual ----------------
// block = 256 thr = 4 waves; block tile 64 rows x 256 cols; wave tile 64x64 (2x2 of 32x32)
__global__ __launch_bounds__(256) void k_layer_mfma(
    const unsigned short* __restrict__ Ahi, const unsigned short* __restrict__ Alo,
    const unsigned short* __restrict__ Bhi, const unsigned short* __restrict__ Blo,
    const float* __restrict__ bias, const float* __restrict__ lng, const float* __restrict__ lnb,
    const float* __restrict__ gamL, const float* __restrict__ betL,
    const int* __restrict__ n_index, float* __restrict__ h, int N){
  __shared__ float2 part[4][64];
  const int tid = threadIdx.x;
  const int w = tid >> 6, l = tid & 63;
  const int half = l >> 5, lcol = l & 31;
  const int row0 = blockIdx.x * 64;
  const int colb = w * 64;

  f32x16 acc[2][2] = {};
  const size_t a0 = (size_t)(row0 + lcol)*HDIM + half*8;
  const size_t b0 = (size_t)(colb + lcol)*HDIM + half*8;

  #pragma unroll 4
  for(int ks=0; ks<16; ks++){
    const int k0 = ks*16;
    short8v ah0 = *(const short8v*)&Ahi[a0 + k0];
    short8v ah1 = *(const short8v*)&Ahi[a0 + 32*HDIM + k0];
    short8v al0 = *(const short8v*)&Alo[a0 + k0];
    short8v al1 = *(const short8v*)&Alo[a0 + 32*HDIM + k0];
    short8v bh0 = *(const short8v*)&Bhi[b0 + k0];
    short8v bh1 = *(const short8v*)&Bhi[b0 + 32*HDIM + k0];
    short8v bl0 = *(const short8v*)&Blo[b0 + k0];
    short8v bl1 = *(const short8v*)&Blo[b0 + 32*HDIM + k0];
    acc[0][0] = __builtin_amdgcn_mfma_f32_32x32x16_bf16(ah0, bh0, acc[0][0], 0,0,0);
    acc[0][1] = __builtin_amdgcn_mfma_f32_32x32x16_bf16(ah0, bh1, acc[0][1], 0,0,0);
    acc[1][0] = __builtin_amdgcn_mfma_f32_32x32x16_bf16(ah1, bh0, acc[1][0], 0,0,0);
    acc[1][1] = __builtin_amdgcn_mfma_f32_32x32x16_bf16(ah1, bh1, acc[1][1], 0,0,0);
    acc[0][0] = __builtin_amdgcn_mfma_f32_32x32x16_bf16(ah0, bl0, acc[0][0], 0,0,0);
    acc[0][1] = __builtin_amdgcn_mfma_f32_32x32x16_bf16(ah0, bl1, acc[0][1], 0,0,0);
    acc[1][0] = __builtin_amdgcn_mfma_f32_32x32x16_bf16(ah1, bl0, acc[1][0], 0,0,0);
    acc[1][1] = __builtin_amdgcn_mfma_f32_32x32x16_bf16(ah1, bl1, acc[1][1], 0,0,0);
    acc[0][0] = __builtin_amdgcn_mfma_f32_32x32x16_bf16(al0, bh0, acc[0][0], 0,0,0);
    acc[0][1] = __builtin_amdgcn_mfma_f32_32x32x16_bf16(al0, bh1, acc[0][1], 0,0,0);
    acc[1][0] = __builtin_amdgcn_mfma_f32_32x32x16_bf16(al1, bh0, acc[1][0], 0,0,0);
    acc[1][1] = __builtin_amdgcn_mfma_f32_32x32x16_bf16(al1, bh1, acc[1][1], 0,0,0);
  }

  // epilogue: bias, LN stats (in-wave 64-col partials -> LDS cross-wave), FiLM, SiLU, residual
  float bias_c[2], lng_c[2], lnb_c[2];
  #pragma unroll
  for(int nt=0; nt<2; nt++){
    const int c = colb + nt*32 + lcol;
    bias_c[nt] = bias[c]; lng_c[nt] = lng[c]; lnb_c[nt] = lnb[c];
  }
  #pragma unroll
  for(int mt=0; mt<2; mt++){
    #pragma unroll
    for(int r=0; r<16; r++){
      float z0 = acc[mt][0][r] + bias_c[0];
      float z1 = acc[mt][1][r] + bias_c[1];
      acc[mt][0][r] = z0; acc[mt][1][r] = z1;
      float s = z0 + z1, q = z0*z0 + z1*z1;
      #pragma unroll
      for(int off=1; off<32; off<<=1){ s += __shfl_xor(s, off, 64); q += __shfl_xor(q, off, 64); }
      const int rl = (r&3) + 8*(r>>2) + 4*half;
      part[w][mt*32 + rl] = make_float2(s, q);
    }
  }
  __syncthreads();

  #pragma unroll
  for(int mt=0; mt<2; mt++){
    #pragma unroll
    for(int r=0; r<16; r++){
      const int rl = (r&3) + 8*(r>>2) + 4*half;
      const int slot = mt*32 + rl;
      float2 t0 = part[0][slot], t1 = part[1][slot], t2 = part[2][slot], t3 = part[3][slot];
      float mu = (t0.x+t1.x+t2.x+t3.x) * (1.f/256.f);
      float ex2 = (t0.y+t1.y+t2.y+t3.y) * (1.f/256.f);
      float rs = rsqrtf(fmaxf(ex2 - mu*mu, 0.f) + 1e-5f);
      const int grow = row0 + mt*32 + rl;
      const bool ok = grow < N;
      const int bidx = ok ? n_index[grow] : 0;
      const float* gp = gamL + (size_t)bidx*HDIM;
      const float* bp = betL + (size_t)bidx*HDIM;
      #pragma unroll
      for(int nt=0; nt<2; nt++){
        const int c = colb + nt*32 + lcol;
        float z = acc[mt][nt][r];
        float zn = (z - mu)*rs*lng_c[nt] + lnb_c[nt];
        float f = zn*(1.f + gp[c]) + bp[c];
        float o = silu_(f);
        if(ok){
          float hv = h[(size_t)grow*HDIM + c];
          h[(size_t)grow*HDIM + c] = o + hv;
        }
      }
    }
  }
}

// ---------------- head ----------------
__global__ __launch_bounds__(256) void k_head(const float* __restrict__ h,
    const float* __restrict__ hw, const int* __restrict__ n_index,
    float* __restrict__ gsum, int* __restrict__ gcnt, int N){
  int v = blockIdx.x*4 + (threadIdx.x>>6);
  if(v >= N) return;
  int lane = threadIdx.x & 63;
  float4 x = *(const float4*)&h[(size_t)v*HDIM + lane*4];
  float4 w = *(const float4*)&hw[lane*4];
  float s = x.x*w.x + x.y*w.y + x.z*w.z + x.w*w.w;
  #pragma unroll
  for(int off=32; off; off>>=1) s += __shfl_xor(s, off, 64);
  if(lane == 0){
    int b = n_index[v];
    atomicAdd(&gsum[b], s);
    atomicAdd(&gcnt[b], 1);
  }
}

__global__ void k_final(const float* __restrict__ gsum, const int* __restrict__ gcnt,
                        const float* __restrict__ hb, float* __restrict__ out, int B){
  int b = blockIdx.x*256 + threadIdx.x;
  if(b < B) out[b] = gsum[b] / (float)max(gcnt[b],1) + hb[0];
}

extern "C" void kernel_launch(void* const* d_in, const int* in_sizes, int n_in,
                              void* d_out, int out_size, void* d_ws, size_t ws_size,
                              hipStream_t stream){
  const float* node_x   = (const float*)d_in[0];
  const float* edge_e   = (const float*)d_in[1];
  const float* t        = (const float*)d_in[2];
  const int*   n_index  = (const int*)d_in[3];
  const int*   src      = (const int*)d_in[4];
  const int*   dst      = (const int*)d_in[5];
  const float* in_conv_w= (const float*)d_in[6];
  const float* in_conv_b= (const float*)d_in[7];
  const float* edge_w   = (const float*)d_in[8];
  const float* edge_b   = (const float*)d_in[9];
  const float* t_w1     = (const float*)d_in[10];
  const float* t_b1     = (const float*)d_in[11];
  const float* t_w2     = (const float*)d_in[12];
  const float* t_b2     = (const float*)d_in[13];
  const float* conv2_w  = (const float*)d_in[16];
  const float* conv2_b  = (const float*)d_in[17];
  const float* ln2_g    = (const float*)d_in[20];
  const float* ln2_b    = (const float*)d_in[21];
  const float* film2_w  = (const float*)d_in[24];
  const float* film2_b  = (const float*)d_in[25];
  const float* head_w   = (const float*)d_in[26];
  const float* head_b   = (const float*)d_in[27];

  const int N = in_sizes[3];
  const int E = in_sizes[4];
  const int B = in_sizes[2];
  const int Npad = (N + 63) & ~63;

  char* w = (char*)d_ws;
  auto alloc = [&](size_t bytes)->char*{
    char* p = w; w += (bytes + 255) & ~(size_t)255; return p;
  };
  int*   cnt_out = (int*)  alloc((size_t)N*4);
  int*   cnt_in  = (int*)  alloc((size_t)N*4);
  float* no      = (float*)alloc((size_t)N*4);
  float* ni      = (float*)alloc((size_t)N*4);
  int*   csr_off = (int*)  alloc((size_t)(N+1)*4);
  int*   csr_pos = (int*)  alloc((size_t)N*4);
  int*   csr_src = (int*)  alloc((size_t)E*4);
  int*   csr_eid = (int*)  alloc((size_t)E*4);
  float* cond    = (float*)alloc((size_t)B*HDIM*4);
  float* gbX     = (float*)alloc((size_t)12*B*HDIM*4);
  float* gsum    = (float*)alloc((size_t)B*4);
  int*   gcnt    = (int*)  alloc((size_t)B*4);
  float* h       = (float*)alloc((size_t)N*HDIM*4);
  unsigned short* agg_hi = (unsigned short*)alloc((size_t)Npad*HDIM*2);
  unsigned short* agg_lo = (unsigned short*)alloc((size_t)Npad*HDIM*2);
  unsigned short* Wthi   = (unsigned short*)alloc((size_t)NLAYERS*HDIM*HDIM*2);
  unsigned short* Wtlo   = (unsigned short*)alloc((size_t)NLAYERS*HDIM*HDIM*2);
  float* wcat    = (float*)alloc((size_t)64*HDIM*4);
  float* A48     = (float*)agg_hi;   // init-stage A (Npad x 64 f32) overlays agg_hi+agg_lo region? no: 25.6MB < 51.2MB, fits in agg_hi alone

  hipMemsetAsync(cnt_out, 0, (size_t)N*4, stream);
  hipMemsetAsync(cnt_in,  0, (size_t)N*4, stream);
  hipMemsetAsync(gsum,    0, (size_t)B*4, stream);
  hipMemsetAsync(gcnt,    0, (size_t)B*4, stream);

  int gE = (E+255)/256, gN = (N+255)/256;
  k_count<<<gE,256,0,stream>>>(src, dst, E, cnt_out, cnt_in);
  k_scan<<<1,1024,0,stream>>>(cnt_in, csr_off, N);
  k_prep<<<gN,256,0,stream>>>(cnt_out, cnt_in, csr_off, no, ni, csr_pos, N);
  k_fill<<<gE,256,0,stream>>>(src, dst, E, csr_pos, csr_src, csr_eid);

  k_cond<<<B,256,0,stream>>>(t, t_w1, t_b1, t_w2, t_b2, cond);
  // gb chunks: 12 x (1024 x 256), chunk c = (layer i = c>>1, gamma/beta half = c&1)
  k_gemm_f32<256><<<dim3(B/64,12),256,0,stream>>>(cond, HDIM, film2_w, 512, film2_b,
                                                  gbX, HDIM, B, 1);

  k_w2b<<<NLAYERS*HDIM*HDIM/256,256,0,stream>>>(conv2_w, Wthi, Wtlo);
  k_wcat<<<64,256,0,stream>>>(in_conv_w, edge_w, edge_b, wcat);
  k_init_agg<<<(N+3)/4,256,0,stream>>>(node_x, edge_e, csr_off, csr_src, csr_eid,
                                       no, ni, cnt_in, A48, N);
  k_gemm_f32<64><<<Npad/64,256,0,stream>>>(A48, 64, wcat, HDIM, in_conv_b, h, HDIM, N, 0);

  for(int i=0;i<NLAYERS;i++){
    k_gather_bf<<<Npad/4,256,0,stream>>>(h, csr_off, csr_src, no, ni, agg_hi, agg_lo, N, Npad);
    k_layer_mfma<<<Npad/64,256,0,stream>>>(agg_hi, agg_lo,
        Wthi + (size_t)i*HDIM*HDIM, Wtlo + (size_t)i*HDIM*HDIM,
        conv2_b + (size_t)i*HDIM,
        ln2_g + (size_t)i*HDIM, ln2_b + (size_t)i*HDIM,
        gbX + (size_t)(2*i)*B*HDIM, gbX + (size_t)(2*i+1)*B*HDIM,
        n_index, h, N);
  }

  k_head<<<(N+3)/4,256,0,stream>>>(h, head_w, n_index, gsum, gcnt, N);
  k_final<<<(B+255)/256,256,0,stream>>>(gsum, gcnt, head_b, (float*)d_out, B);
}

// Round 3
// 2030.356 us; speedup vs baseline: 1.3606x; 1.1284x over previous
//
#include <hip/hip_runtime.h>
#include <math.h>

#define HDIM 256
#define NLAYERS 6

typedef __attribute__((ext_vector_type(8))) short short8v;
typedef __attribute__((ext_vector_type(16))) float f32x16;

__device__ __forceinline__ float silu_(float x){ return x * (1.f/(1.f+__expf(-x))); }

__device__ __forceinline__ unsigned short f2bf(float f){
  unsigned u = __float_as_uint(f);
  u += 0x7FFF + ((u>>16)&1);
  return (unsigned short)(u>>16);
}
__device__ __forceinline__ float bf2f(unsigned short b){ return __uint_as_float(((unsigned)b)<<16); }

__device__ __forceinline__ void gload_lds16(const void* g, void* l){
  __builtin_amdgcn_global_load_lds((const __attribute__((address_space(1))) void*)g,
                                   (__attribute__((address_space(3))) void*)l, 16, 0, 0);
}

// ---------------- degree counting ----------------
__global__ void k_count(const int* __restrict__ src, const int* __restrict__ dst, int E,
                        int* __restrict__ cnt_out, int* __restrict__ cnt_in){
  int e = blockIdx.x*256 + threadIdx.x;
  if(e < E){
    atomicAdd(&cnt_out[src[e]], 1);
    atomicAdd(&cnt_in[dst[e]], 1);
  }
}

// ---------------- exclusive scan of cnt_in -> csr_off (single block) ----------------
__global__ __launch_bounds__(1024) void k_scan(const int* __restrict__ cnt_in,
                                               int* __restrict__ csr_off, int N){
  __shared__ int s[1024];
  int t = threadIdx.x;
  int chunk = (N + 1023) >> 10;
  int b0 = t * chunk;
  int loc = 0;
  for(int j=0;j<chunk;j++){ int i=b0+j; if(i<N) loc += cnt_in[i]; }
  s[t] = loc; __syncthreads();
  for(int off=1; off<1024; off<<=1){
    int v = (t>=off) ? s[t-off] : 0;
    __syncthreads();
    s[t] += v;
    __syncthreads();
  }
  int run = (t==0) ? 0 : s[t-1];
  for(int j=0;j<chunk;j++){
    int i=b0+j;
    if(i<N){ csr_off[i] = run; run += cnt_in[i]; }
  }
  if(t==1023) csr_off[N] = run;
}

// ---------------- norms + csr fill pointer ----------------
__global__ void k_prep(const int* __restrict__ cnt_out, const int* __restrict__ cnt_in,
                       const int* __restrict__ csr_off,
                       float* __restrict__ no, float* __restrict__ ni,
                       int* __restrict__ csr_pos, int N){
  int v = blockIdx.x*256 + threadIdx.x;
  if(v < N){
    no[v] = rsqrtf((float)max(cnt_out[v],1));
    ni[v] = rsqrtf((float)max(cnt_in[v],1));
    csr_pos[v] = csr_off[v];
  }
}

__global__ void k_fill(const int* __restrict__ src, const int* __restrict__ dst, int E,
                       int* __restrict__ csr_pos, int* __restrict__ csr_src,
                       int* __restrict__ csr_eid){
  int e = blockIdx.x*256 + threadIdx.x;
  if(e < E){
    int p = atomicAdd(&csr_pos[dst[e]], 1);
    csr_src[p] = src[e];
    csr_eid[p] = e;
  }
}

// ---------------- time embedding + MLP -> cond ----------------
__global__ __launch_bounds__(256) void k_cond(const float* __restrict__ t,
        const float* __restrict__ w1, const float* __restrict__ b1,
        const float* __restrict__ w2, const float* __restrict__ b2,
        float* __restrict__ cond){
  __shared__ float emb[128];
  __shared__ float hid[256];
  int b = blockIdx.x, tid = threadIdx.x;
  float tv = t[b] * 1000.f;
  if(tid < 128){
    int k = tid & 63;
    float fr = expf(-logf(1000.f) * (float)k * (1.f/64.f));
    float a = tv * fr;
    emb[tid] = (tid < 64) ? sinf(a) : cosf(a);
  }
  __syncthreads();
  {
    float s = b1[tid];
    for(int k=0;k<128;k++) s += emb[k] * w1[k*HDIM + tid];
    hid[tid] = silu_(s);
  }
  __syncthreads();
  {
    float s = b2[tid];
    for(int k=0;k<256;k++) s += hid[k] * w2[k*HDIM + tid];
    cond[(size_t)b*HDIM + tid] = s;
  }
}

// ---------------- generic f32 tiled GEMM: 64 rows x 256 cols per block ----------------
template<int K>
__global__ __launch_bounds__(256) void k_gemm_f32(
    const float* __restrict__ A, int lda,
    const float* __restrict__ W, int ldw,
    const float* __restrict__ bias,
    float* __restrict__ out, int ldo, int M, int mode){
  if(mode == 1){
    int c = blockIdx.y;
    W    += (size_t)(c>>1)*131072 + (size_t)(c&1)*256;
    bias += (size_t)(c>>1)*512 + (size_t)(c&1)*256;
    out  += (size_t)c*1024*256;
  }
  __shared__ float As[64][36];
  __shared__ float Ws[32][256];
  const int tid = threadIdx.x;
  const int rg = tid >> 4;
  const int cg = tid & 15;
  const int row0 = blockIdx.x * 64;

  float4 acc[4][4];
  #pragma unroll
  for(int i=0;i<4;i++)
    #pragma unroll
    for(int m=0;m<4;m++) acc[i][m] = make_float4(0.f,0.f,0.f,0.f);

  const int ar = tid >> 2;
  const int ac = (tid & 3) * 8;
  const int wr = tid >> 3;
  const int wc = (tid & 7) * 32;

  for(int kk=0; kk<K; kk+=32){
    {
      int gr = row0 + ar;
      float4 v0 = make_float4(0.f,0.f,0.f,0.f), v1 = v0;
      if(gr < M){
        v0 = *(const float4*)&A[(size_t)gr*lda + kk + ac];
        v1 = *(const float4*)&A[(size_t)gr*lda + kk + ac + 4];
      }
      *(float4*)&As[ar][ac]   = v0;
      *(float4*)&As[ar][ac+4] = v1;
    }
    #pragma unroll
    for(int u=0;u<8;u++)
      *(float4*)&Ws[wr][wc + u*4] = *(const float4*)&W[(size_t)(kk+wr)*ldw + wc + u*4];
    __syncthreads();
    #pragma unroll 8
    for(int k=0;k<32;k++){
      float a0 = As[rg*4+0][k];
      float a1 = As[rg*4+1][k];
      float a2 = As[rg*4+2][k];
      float a3 = As[rg*4+3][k];
      #pragma unroll
      for(int m=0;m<4;m++){
        float4 w = *(const float4*)&Ws[k][cg*4 + m*64];
        acc[0][m].x += a0*w.x; acc[0][m].y += a0*w.y; acc[0][m].z += a0*w.z; acc[0][m].w += a0*w.w;
        acc[1][m].x += a1*w.x; acc[1][m].y += a1*w.y; acc[1][m].z += a1*w.z; acc[1][m].w += a1*w.w;
        acc[2][m].x += a2*w.x; acc[2][m].y += a2*w.y; acc[2][m].z += a2*w.z; acc[2][m].w += a2*w.w;
        acc[3][m].x += a3*w.x; acc[3][m].y += a3*w.y; acc[3][m].z += a3*w.z; acc[3][m].w += a3*w.w;
      }
    }
    __syncthreads();
  }

  const int c0 = cg * 4;
  #pragma unroll
  for(int i=0;i<4;i++){
    const int gr = row0 + rg*4 + i;
    if(gr >= M) continue;
    #pragma unroll
    for(int m=0;m<4;m++){
      const int c = c0 + m*64;
      float4 b4 = *(const float4*)&bias[c];
      float4 o = make_float4(acc[i][m].x+b4.x, acc[i][m].y+b4.y,
                             acc[i][m].z+b4.z, acc[i][m].w+b4.w);
      *(float4*)&out[(size_t)gr*ldo + c] = o;
    }
  }
}

// ---------------- build stacked init weight [64][256] ----------------
__global__ void k_wcat(const float* __restrict__ in_w, const float* __restrict__ ew,
                       const float* __restrict__ eb, float* __restrict__ wcat){
  int idx = blockIdx.x*256 + threadIdx.x;
  int r = idx>>8, c = idx&255;
  float v = 0.f;
  if(r < 32) v = in_w[r*HDIM + c];
  else if(r < 48) v = ew[(r-32)*HDIM + c];
  else if(r == 48) v = eb[c];
  wcat[idx] = v;
}

// ---------------- prepack conv2_w: transpose + bf16 hi/lo split ----------------
__global__ void k_w2b(const float* __restrict__ W, unsigned short* __restrict__ hi_,
                      unsigned short* __restrict__ lo_){
  int idx = blockIdx.x*256 + threadIdx.x;   // 6*65536
  int i = idx >> 16, r = idx & 65535;
  int n = r >> 8, k = r & 255;
  float v = W[((size_t)i*256 + k)*256 + n];
  unsigned short h = f2bf(v);
  float lo = v - bf2f(h);
  hi_[((size_t)i*256 + n)*256 + k] = h;
  lo_[((size_t)i*256 + n)*256 + k] = f2bf(lo);
}

// ---------------- init aggregation ----------------
__global__ __launch_bounds__(256) void k_init_agg(const float* __restrict__ node_x,
    const float* __restrict__ edge_e,
    const int* __restrict__ csr_off, const int* __restrict__ csr_src, const int* __restrict__ csr_eid,
    const float* __restrict__ no, const float* __restrict__ ni, const int* __restrict__ cnt_in,
    float* __restrict__ A48, int N){
  int v = blockIdx.x*4 + (threadIdx.x>>6);
  if(v >= N) return;
  int lane = threadIdx.x & 63;
  int beg = csr_off[v], end = csr_off[v+1];
  float acc = 0.f;
  for(int p=beg; p<end; p++){
    int s = csr_src[p]; int e = csr_eid[p];
    if(lane < 32)      acc += node_x[(size_t)s*32 + lane] * no[s];
    else if(lane < 48) acc += edge_e[(size_t)e*16 + (lane-32)];
  }
  int ci = cnt_in[v];
  float out;
  if(lane < 32)      out = acc * ni[v];
  else if(lane < 48) out = acc * (1.f/(float)max(ci,1));
  else if(lane == 48) out = (ci>0) ? 1.f : 0.f;
  else out = 0.f;
  A48[(size_t)v*64 + lane] = out;
}

// ---------------- per-layer gather -> bf16 hi/lo ----------------
__global__ __launch_bounds__(256) void k_gather_bf(const float* __restrict__ h,
   const int* __restrict__ csr_off, const int* __restrict__ csr_src,
   const float* __restrict__ no, const float* __restrict__ ni,
   unsigned short* __restrict__ ahi, unsigned short* __restrict__ alo, int N, int Npad){
  int v = blockIdx.x*4 + (threadIdx.x>>6);
  if(v >= Npad) return;
  int lane = threadIdx.x & 63;
  float4 acc = make_float4(0.f,0.f,0.f,0.f);
  if(v < N){
    int beg = csr_off[v], end = csr_off[v+1];
    for(int p=beg; p<end; p++){
      int s = csr_src[p];
      float w = no[s];
      float4 x = *(const float4*)&h[(size_t)s*HDIM + lane*4];
      acc.x += x.x*w; acc.y += x.y*w; acc.z += x.z*w; acc.w += x.w*w;
    }
    float sc = ni[v];
    acc.x*=sc; acc.y*=sc; acc.z*=sc; acc.w*=sc;
  }
  unsigned short h0 = f2bf(acc.x), h1 = f2bf(acc.y), h2 = f2bf(acc.z), h3 = f2bf(acc.w);
  ushort4 hv = make_ushort4(h0,h1,h2,h3);
  ushort4 lv = make_ushort4(f2bf(acc.x - bf2f(h0)), f2bf(acc.y - bf2f(h1)),
                            f2bf(acc.z - bf2f(h2)), f2bf(acc.w - bf2f(h3)));
  *(ushort4*)&ahi[(size_t)v*HDIM + lane*4] = hv;
  *(ushort4*)&alo[(size_t)v*HDIM + lane*4] = lv;
}

// ---------------- layer GEMM: bf16 MFMA 3-term hi/lo, LDS-staged A, fused epilogue ----------------
// block = 256 thr = 4 waves; tile 64 rows x 256 cols; wave tile 64x64 (2x2 of 32x32)
// A staged via global_load_lds (double-buffered K-chunks of 64), XOR-swizzled.
__global__ __launch_bounds__(256) void k_layer_mfma(
    const unsigned short* __restrict__ Ahi, const unsigned short* __restrict__ Alo,
    const unsigned short* __restrict__ Bhi, const unsigned short* __restrict__ Blo,
    const float* __restrict__ bias, const float* __restrict__ lng, const float* __restrict__ lnb,
    const float* __restrict__ gamL, const float* __restrict__ betL,
    const int* __restrict__ n_index, float* __restrict__ h, int N){
  __shared__ __align__(16) unsigned short AsH[2][4096];  // [buf][row*64 + k], swizzled
  __shared__ __align__(16) unsigned short AsL[2][4096];
  __shared__ float2 part[4][64];
  const int tid = threadIdx.x;
  const int w = tid >> 6, l = tid & 63;
  const int half = l >> 5, lcol = l & 31;
  const int row0 = blockIdx.x * 64;
  const int colb = w * 64;

  // stage K-chunk c (64 k-elems) of A hi+lo into buffer b.
  // LDS linear dest; global src pre-swizzled: byte_off ^= ((l&7)^(l>>3))<<4 (involution).
  auto stage = [&](int c, int b){
    const int swzk = ((l&7) ^ (l>>3)) << 3;   // element offset after swizzle
    #pragma unroll
    for(int i=0;i<2;i++){
      const int r = w*16 + i*8;  // wave-uniform part of row
      const size_t src = (size_t)(row0 + r + (l>>3))*HDIM + c*64 + swzk;
      gload_lds16(&Ahi[src], &AsH[b][r*64]);
      gload_lds16(&Alo[src], &AsL[b][r*64]);
    }
  };

  f32x16 acc[2][2] = {};
  const size_t bb = (size_t)(colb + lcol)*HDIM + half*8;
  const int swz = (lcol & 7) << 4;            // read-side swizzle (bytes)

  // prologue: stage chunk 0, prefetch B for t=0
  stage(0, 0);
  short8v bh0 = *(const short8v*)&Bhi[bb];
  short8v bh1 = *(const short8v*)&Bhi[bb + 32*HDIM];
  short8v bl0 = *(const short8v*)&Blo[bb];
  short8v bl1 = *(const short8v*)&Blo[bb + 32*HDIM];
  __syncthreads();

  #pragma unroll
  for(int t=0; t<16; t++){
    const int c = t>>2, ks = t&3, b = c&1;
    if(ks==0 && c<3) stage(c+1, (c+1)&1);
    // prefetch B for t+1
    short8v nbh0, nbh1, nbl0, nbl1;
    if(t < 15){
      const int tn = t+1;
      const int ko = (tn>>2)*64 + (tn&3)*16;
      nbh0 = *(const short8v*)&Bhi[bb + ko];
      nbh1 = *(const short8v*)&Bhi[bb + 32*HDIM + ko];
      nbl0 = *(const short8v*)&Blo[bb + ko];
      nbl1 = *(const short8v*)&Blo[bb + 32*HDIM + ko];
    }
    // A fragments from LDS (swizzled ds_read_b128)
    const int kb = (ks*32 + half*16) ^ swz;
    const char* baseH = (const char*)AsH[b];
    const char* baseL = (const char*)AsL[b];
    short8v ah0 = *(const short8v*)(baseH + lcol*128 + kb);
    short8v ah1 = *(const short8v*)(baseH + (32+lcol)*128 + kb);
    short8v al0 = *(const short8v*)(baseL + lcol*128 + kb);
    short8v al1 = *(const short8v*)(baseL + (32+lcol)*128 + kb);

    acc[0][0] = __builtin_amdgcn_mfma_f32_32x32x16_bf16(ah0, bh0, acc[0][0], 0,0,0);
    acc[0][1] = __builtin_amdgcn_mfma_f32_32x32x16_bf16(ah0, bh1, acc[0][1], 0,0,0);
    acc[1][0] = __builtin_amdgcn_mfma_f32_32x32x16_bf16(ah1, bh0, acc[1][0], 0,0,0);
    acc[1][1] = __builtin_amdgcn_mfma_f32_32x32x16_bf16(ah1, bh1, acc[1][1], 0,0,0);
    acc[0][0] = __builtin_amdgcn_mfma_f32_32x32x16_bf16(ah0, bl0, acc[0][0], 0,0,0);
    acc[0][1] = __builtin_amdgcn_mfma_f32_32x32x16_bf16(ah0, bl1, acc[0][1], 0,0,0);
    acc[1][0] = __builtin_amdgcn_mfma_f32_32x32x16_bf16(ah1, bl0, acc[1][0], 0,0,0);
    acc[1][1] = __builtin_amdgcn_mfma_f32_32x32x16_bf16(ah1, bl1, acc[1][1], 0,0,0);
    acc[0][0] = __builtin_amdgcn_mfma_f32_32x32x16_bf16(al0, bh0, acc[0][0], 0,0,0);
    acc[0][1] = __builtin_amdgcn_mfma_f32_32x32x16_bf16(al0, bh1, acc[0][1], 0,0,0);
    acc[1][0] = __builtin_amdgcn_mfma_f32_32x32x16_bf16(al1, bh0, acc[1][0], 0,0,0);
    acc[1][1] = __builtin_amdgcn_mfma_f32_32x32x16_bf16(al1, bh1, acc[1][1], 0,0,0);

    bh0 = nbh0; bh1 = nbh1; bl0 = nbl0; bl1 = nbl1;
    if(ks==3 && t<15) __syncthreads();
  }

  // epilogue: bias, LN stats (in-wave partials -> LDS cross-wave), FiLM, SiLU, residual
  float bias_c[2], lng_c[2], lnb_c[2];
  #pragma unroll
  for(int nt=0; nt<2; nt++){
    const int c = colb + nt*32 + lcol;
    bias_c[nt] = bias[c]; lng_c[nt] = lng[c]; lnb_c[nt] = lnb[c];
  }
  #pragma unroll
  for(int mt=0; mt<2; mt++){
    #pragma unroll
    for(int r=0; r<16; r++){
      float z0 = acc[mt][0][r] + bias_c[0];
      float z1 = acc[mt][1][r] + bias_c[1];
      acc[mt][0][r] = z0; acc[mt][1][r] = z1;
      float s = z0 + z1, q = z0*z0 + z1*z1;
      #pragma unroll
      for(int off=1; off<32; off<<=1){ s += __shfl_xor(s, off, 64); q += __shfl_xor(q, off, 64); }
      const int rl = (r&3) + 8*(r>>2) + 4*half;
      part[w][mt*32 + rl] = make_float2(s, q);
    }
  }
  __syncthreads();

  #pragma unroll
  for(int mt=0; mt<2; mt++){
    #pragma unroll
    for(int r=0; r<16; r++){
      const int rl = (r&3) + 8*(r>>2) + 4*half;
      const int slot = mt*32 + rl;
      float2 t0 = part[0][slot], t1 = part[1][slot], t2 = part[2][slot], t3 = part[3][slot];
      float mu = (t0.x+t1.x+t2.x+t3.x) * (1.f/256.f);
      float ex2 = (t0.y+t1.y+t2.y+t3.y) * (1.f/256.f);
      float rs = rsqrtf(fmaxf(ex2 - mu*mu, 0.f) + 1e-5f);
      const int grow = row0 + mt*32 + rl;
      const bool ok = grow < N;
      const int bidx = ok ? n_index[grow] : 0;
      const float* gp = gamL + (size_t)bidx*HDIM;
      const float* bp = betL + (size_t)bidx*HDIM;
      #pragma unroll
      for(int nt=0; nt<2; nt++){
        const int c = colb + nt*32 + lcol;
        float z = acc[mt][nt][r];
        float zn = (z - mu)*rs*lng_c[nt] + lnb_c[nt];
        float f = zn*(1.f + gp[c]) + bp[c];
        float o = silu_(f);
        if(ok){
          float hv = h[(size_t)grow*HDIM + c];
          h[(size_t)grow*HDIM + c] = o + hv;
        }
      }
    }
  }
}

// ---------------- head ----------------
__global__ __launch_bounds__(256) void k_head(const float* __restrict__ h,
    const float* __restrict__ hw, const int* __restrict__ n_index,
    float* __restrict__ gsum, int* __restrict__ gcnt, int N){
  int v = blockIdx.x*4 + (threadIdx.x>>6);
  if(v >= N) return;
  int lane = threadIdx.x & 63;
  float4 x = *(const float4*)&h[(size_t)v*HDIM + lane*4];
  float4 w = *(const float4*)&hw[lane*4];
  float s = x.x*w.x + x.y*w.y + x.z*w.z + x.w*w.w;
  #pragma unroll
  for(int off=32; off; off>>=1) s += __shfl_xor(s, off, 64);
  if(lane == 0){
    int b = n_index[v];
    atomicAdd(&gsum[b], s);
    atomicAdd(&gcnt[b], 1);
  }
}

__global__ void k_final(const float* __restrict__ gsum, const int* __restrict__ gcnt,
                        const float* __restrict__ hb, float* __restrict__ out, int B){
  int b = blockIdx.x*256 + threadIdx.x;
  if(b < B) out[b] = gsum[b] / (float)max(gcnt[b],1) + hb[0];
}

extern "C" void kernel_launch(void* const* d_in, const int* in_sizes, int n_in,
                              void* d_out, int out_size, void* d_ws, size_t ws_size,
                              hipStream_t stream){
  const float* node_x   = (const float*)d_in[0];
  const float* edge_e   = (const float*)d_in[1];
  const float* t        = (const float*)d_in[2];
  const int*   n_index  = (const int*)d_in[3];
  const int*   src      = (const int*)d_in[4];
  const int*   dst      = (const int*)d_in[5];
  const float* in_conv_w= (const float*)d_in[6];
  const float* in_conv_b= (const float*)d_in[7];
  const float* edge_w   = (const float*)d_in[8];
  const float* edge_b   = (const float*)d_in[9];
  const float* t_w1     = (const float*)d_in[10];
  const float* t_b1     = (const float*)d_in[11];
  const float* t_w2     = (const float*)d_in[12];
  const float* t_b2     = (const float*)d_in[13];
  const float* conv2_w  = (const float*)d_in[16];
  const float* conv2_b  = (const float*)d_in[17];
  const float* ln2_g    = (const float*)d_in[20];
  const float* ln2_b    = (const float*)d_in[21];
  const float* film2_w  = (const float*)d_in[24];
  const float* film2_b  = (const float*)d_in[25];
  const float* head_w   = (const float*)d_in[26];
  const float* head_b   = (const float*)d_in[27];

  const int N = in_sizes[3];
  const int E = in_sizes[4];
  const int B = in_sizes[2];
  const int Npad = (N + 63) & ~63;

  char* w = (char*)d_ws;
  auto alloc = [&](size_t bytes)->char*{
    char* p = w; w += (bytes + 255) & ~(size_t)255; return p;
  };
  int*   cnt_out = (int*)  alloc((size_t)N*4);
  int*   cnt_in  = (int*)  alloc((size_t)N*4);
  float* no      = (float*)alloc((size_t)N*4);
  float* ni      = (float*)alloc((size_t)N*4);
  int*   csr_off = (int*)  alloc((size_t)(N+1)*4);
  int*   csr_pos = (int*)  alloc((size_t)N*4);
  int*   csr_src = (int*)  alloc((size_t)E*4);
  int*   csr_eid = (int*)  alloc((size_t)E*4);
  float* cond    = (float*)alloc((size_t)B*HDIM*4);
  float* gbX     = (float*)alloc((size_t)12*B*HDIM*4);
  float* gsum    = (float*)alloc((size_t)B*4);
  int*   gcnt    = (int*)  alloc((size_t)B*4);
  float* h       = (float*)alloc((size_t)N*HDIM*4);
  unsigned short* agg_hi = (unsigned short*)alloc((size_t)Npad*HDIM*2);
  unsigned short* agg_lo = (unsigned short*)alloc((size_t)Npad*HDIM*2);
  unsigned short* Wthi   = (unsigned short*)alloc((size_t)NLAYERS*HDIM*HDIM*2);
  unsigned short* Wtlo   = (unsigned short*)alloc((size_t)NLAYERS*HDIM*HDIM*2);
  float* wcat    = (float*)alloc((size_t)64*HDIM*4);
  float* A48     = (float*)agg_hi;   // init-stage A (Npad x 64 f32) fits in agg_hi region

  hipMemsetAsync(cnt_out, 0, (size_t)N*4, stream);
  hipMemsetAsync(cnt_in,  0, (size_t)N*4, stream);
  hipMemsetAsync(gsum,    0, (size_t)B*4, stream);
  hipMemsetAsync(gcnt,    0, (size_t)B*4, stream);

  int gE = (E+255)/256, gN = (N+255)/256;
  k_count<<<gE,256,0,stream>>>(src, dst, E, cnt_out, cnt_in);
  k_scan<<<1,1024,0,stream>>>(cnt_in, csr_off, N);
  k_prep<<<gN,256,0,stream>>>(cnt_out, cnt_in, csr_off, no, ni, csr_pos, N);
  k_fill<<<gE,256,0,stream>>>(src, dst, E, csr_pos, csr_src, csr_eid);

  k_cond<<<B,256,0,stream>>>(t, t_w1, t_b1, t_w2, t_b2, cond);
  // gb chunks: 12 x (1024 x 256), chunk c = (layer i = c>>1, gamma/beta half = c&1)
  k_gemm_f32<256><<<dim3(B/64,12),256,0,stream>>>(cond, HDIM, film2_w, 512, film2_b,
                                                  gbX, HDIM, B, 1);

  k_w2b<<<NLAYERS*HDIM*HDIM/256,256,0,stream>>>(conv2_w, Wthi, Wtlo);
  k_wcat<<<64,256,0,stream>>>(in_conv_w, edge_w, edge_b, wcat);
  k_init_agg<<<(N+3)/4,256,0,stream>>>(node_x, edge_e, csr_off, csr_src, csr_eid,
                                       no, ni, cnt_in, A48, N);
  k_gemm_f32<64><<<Npad/64,256,0,stream>>>(A48, 64, wcat, HDIM, in_conv_b, h, HDIM, N, 0);

  for(int i=0;i<NLAYERS;i++){
    k_gather_bf<<<Npad/4,256,0,stream>>>(h, csr_off, csr_src, no, ni, agg_hi, agg_lo, N, Npad);
    k_layer_mfma<<<Npad/64,256,0,stream>>>(agg_hi, agg_lo,
        Wthi + (size_t)i*HDIM*HDIM, Wtlo + (size_t)i*HDIM*HDIM,
        conv2_b + (size_t)i*HDIM,
        ln2_g + (size_t)i*HDIM, ln2_b + (size_t)i*HDIM,
        gbX + (size_t)(2*i)*B*HDIM, gbX + (size_t)(2*i+1)*B*HDIM,
        n_index, h, N);
  }

  k_head<<<(N+3)/4,256,0,stream>>>(h, head_w, n_index, gsum, gcnt, N);
  k_final<<<(B+255)/256,256,0,stream>>>(gsum, gcnt, head_b, (float*)d_out, B);
}

// Round 4
// 1866.640 us; speedup vs baseline: 1.4799x; 1.0877x over previous
//
#include <hip/hip_runtime.h>
#include <math.h>

#define HDIM 256
#define NLAYERS 6

typedef __attribute__((ext_vector_type(8))) short short8v;
typedef __attribute__((ext_vector_type(16))) float f32x16;

__device__ __forceinline__ float silu_(float x){ return x * (1.f/(1.f+__expf(-x))); }

__device__ __forceinline__ unsigned short f2bf(float f){
  unsigned u = __float_as_uint(f);
  u += 0x7FFF + ((u>>16)&1);
  return (unsigned short)(u>>16);
}
__device__ __forceinline__ float bf2f(unsigned short b){ return __uint_as_float(((unsigned)b)<<16); }

__device__ __forceinline__ void gload_lds16(const void* g, void* l){
  __builtin_amdgcn_global_load_lds((const __attribute__((address_space(1))) void*)g,
                                   (__attribute__((address_space(3))) void*)l, 16, 0, 0);
}

// ---------------- degree counting ----------------
__global__ void k_count(const int* __restrict__ src, const int* __restrict__ dst, int E,
                        int* __restrict__ cnt_out, int* __restrict__ cnt_in){
  int e = blockIdx.x*256 + threadIdx.x;
  if(e < E){
    atomicAdd(&cnt_out[src[e]], 1);
    atomicAdd(&cnt_in[dst[e]], 1);
  }
}

// ---------------- multi-block exclusive scan of cnt_in -> csr_off ----------------
// scan1: per-block (1024 elems) sums -> partial[b]
__global__ __launch_bounds__(256) void k_scan1(const int* __restrict__ cnt_in,
                                               int* __restrict__ partial, int N){
  __shared__ int s[256];
  int b = blockIdx.x, tid = threadIdx.x;
  int i0 = b*1024 + tid*4;
  int sum = 0;
  #pragma unroll
  for(int j=0;j<4;j++){ int i=i0+j; if(i<N) sum += cnt_in[i]; }
  s[tid] = sum; __syncthreads();
  for(int off=128; off; off>>=1){ if(tid<off) s[tid]+=s[tid+off]; __syncthreads(); }
  if(tid==0) partial[b] = s[0];
}
// scan2: single block scans <=256 partials in place (exclusive); writes csr_off[N]=total
__global__ __launch_bounds__(256) void k_scan2(int* __restrict__ partial,
                                               int* __restrict__ csr_off, int nb, int N){
  __shared__ int s[256];
  int tid = threadIdx.x;
  int v = (tid<nb) ? partial[tid] : 0;
  s[tid] = v; __syncthreads();
  for(int off=1; off<256; off<<=1){
    int t = (tid>=off) ? s[tid-off] : 0;
    __syncthreads(); s[tid] += t; __syncthreads();
  }
  if(tid<nb) partial[tid] = s[tid] - v;
  if(tid==255) csr_off[N] = s[255];
}
// scan3: per-block local exclusive scan + block offset
__global__ __launch_bounds__(256) void k_scan3(const int* __restrict__ cnt_in,
                                               const int* __restrict__ partial,
                                               int* __restrict__ csr_off, int N){
  __shared__ int s[256];
  int b = blockIdx.x, tid = threadIdx.x;
  int i0 = b*1024 + tid*4;
  int c[4];
  #pragma unroll
  for(int j=0;j<4;j++){ int i=i0+j; c[j] = (i<N) ? cnt_in[i] : 0; }
  int tot = c[0]+c[1]+c[2]+c[3];
  s[tid] = tot; __syncthreads();
  for(int off=1; off<256; off<<=1){
    int t = (tid>=off) ? s[tid-off] : 0;
    __syncthreads(); s[tid] += t; __syncthreads();
  }
  int run = s[tid] - tot + partial[b];
  #pragma unroll
  for(int j=0;j<4;j++){
    int i = i0+j;
    if(i<N) csr_off[i] = run;
    run += c[j];
  }
}

// ---------------- norms + csr fill pointer + per-graph node count ----------------
__global__ void k_prep(const int* __restrict__ cnt_out, const int* __restrict__ cnt_in,
                       const int* __restrict__ csr_off, const int* __restrict__ n_index,
                       float* __restrict__ no, float* __restrict__ ni,
                       int* __restrict__ csr_pos, int* __restrict__ gcnt, int N){
  int v = blockIdx.x*256 + threadIdx.x;
  if(v < N){
    no[v] = rsqrtf((float)max(cnt_out[v],1));
    ni[v] = rsqrtf((float)max(cnt_in[v],1));
    csr_pos[v] = csr_off[v];
    atomicAdd(&gcnt[n_index[v]], 1);
  }
}

__global__ void k_fill(const int* __restrict__ src, const int* __restrict__ dst, int E,
                       int* __restrict__ csr_pos, int* __restrict__ csr_src,
                       int* __restrict__ csr_eid){
  int e = blockIdx.x*256 + threadIdx.x;
  if(e < E){
    int p = atomicAdd(&csr_pos[dst[e]], 1);
    csr_src[p] = src[e];
    csr_eid[p] = e;
  }
}

// ---------------- time embedding + MLP -> cond ----------------
__global__ __launch_bounds__(256) void k_cond(const float* __restrict__ t,
        const float* __restrict__ w1, const float* __restrict__ b1,
        const float* __restrict__ w2, const float* __restrict__ b2,
        float* __restrict__ cond){
  __shared__ float emb[128];
  __shared__ float hid[256];
  int b = blockIdx.x, tid = threadIdx.x;
  float tv = t[b] * 1000.f;
  if(tid < 128){
    int k = tid & 63;
    float fr = expf(-logf(1000.f) * (float)k * (1.f/64.f));
    float a = tv * fr;
    emb[tid] = (tid < 64) ? sinf(a) : cosf(a);
  }
  __syncthreads();
  {
    float s = b1[tid];
    for(int k=0;k<128;k++) s += emb[k] * w1[k*HDIM + tid];
    hid[tid] = silu_(s);
  }
  __syncthreads();
  {
    float s = b2[tid];
    for(int k=0;k<256;k++) s += hid[k] * w2[k*HDIM + tid];
    cond[(size_t)b*HDIM + tid] = s;
  }
}

// ---------------- generic f32 tiled GEMM: 64 rows x 256 cols per block ----------------
template<int K>
__global__ __launch_bounds__(256) void k_gemm_f32(
    const float* __restrict__ A, int lda,
    const float* __restrict__ W, int ldw,
    const float* __restrict__ bias,
    float* __restrict__ out, int ldo, int M, int mode){
  if(mode == 1){
    int c = blockIdx.y;
    W    += (size_t)(c>>1)*131072 + (size_t)(c&1)*256;
    bias += (size_t)(c>>1)*512 + (size_t)(c&1)*256;
    out  += (size_t)c*1024*256;
  }
  __shared__ float As[64][36];
  __shared__ float Ws[32][256];
  const int tid = threadIdx.x;
  const int rg = tid >> 4;
  const int cg = tid & 15;
  const int row0 = blockIdx.x * 64;

  float4 acc[4][4];
  #pragma unroll
  for(int i=0;i<4;i++)
    #pragma unroll
    for(int m=0;m<4;m++) acc[i][m] = make_float4(0.f,0.f,0.f,0.f);

  const int ar = tid >> 2;
  const int ac = (tid & 3) * 8;
  const int wr = tid >> 3;
  const int wc = (tid & 7) * 32;

  for(int kk=0; kk<K; kk+=32){
    {
      int gr = row0 + ar;
      float4 v0 = make_float4(0.f,0.f,0.f,0.f), v1 = v0;
      if(gr < M){
        v0 = *(const float4*)&A[(size_t)gr*lda + kk + ac];
        v1 = *(const float4*)&A[(size_t)gr*lda + kk + ac + 4];
      }
      *(float4*)&As[ar][ac]   = v0;
      *(float4*)&As[ar][ac+4] = v1;
    }
    #pragma unroll
    for(int u=0;u<8;u++)
      *(float4*)&Ws[wr][wc + u*4] = *(const float4*)&W[(size_t)(kk+wr)*ldw + wc + u*4];
    __syncthreads();
    #pragma unroll 8
    for(int k=0;k<32;k++){
      float a0 = As[rg*4+0][k];
      float a1 = As[rg*4+1][k];
      float a2 = As[rg*4+2][k];
      float a3 = As[rg*4+3][k];
      #pragma unroll
      for(int m=0;m<4;m++){
        float4 w = *(const float4*)&Ws[k][cg*4 + m*64];
        acc[0][m].x += a0*w.x; acc[0][m].y += a0*w.y; acc[0][m].z += a0*w.z; acc[0][m].w += a0*w.w;
        acc[1][m].x += a1*w.x; acc[1][m].y += a1*w.y; acc[1][m].z += a1*w.z; acc[1][m].w += a1*w.w;
        acc[2][m].x += a2*w.x; acc[2][m].y += a2*w.y; acc[2][m].z += a2*w.z; acc[2][m].w += a2*w.w;
        acc[3][m].x += a3*w.x; acc[3][m].y += a3*w.y; acc[3][m].z += a3*w.z; acc[3][m].w += a3*w.w;
      }
    }
    __syncthreads();
  }

  const int c0 = cg * 4;
  #pragma unroll
  for(int i=0;i<4;i++){
    const int gr = row0 + rg*4 + i;
    if(gr >= M) continue;
    #pragma unroll
    for(int m=0;m<4;m++){
      const int c = c0 + m*64;
      float4 b4 = *(const float4*)&bias[c];
      float4 o = make_float4(acc[i][m].x+b4.x, acc[i][m].y+b4.y,
                             acc[i][m].z+b4.z, acc[i][m].w+b4.w);
      *(float4*)&out[(size_t)gr*ldo + c] = o;
    }
  }
}

// ---------------- build stacked init weight [64][256] ----------------
__global__ void k_wcat(const float* __restrict__ in_w, const float* __restrict__ ew,
                       const float* __restrict__ eb, float* __restrict__ wcat){
  int idx = blockIdx.x*256 + threadIdx.x;
  int r = idx>>8, c = idx&255;
  float v = 0.f;
  if(r < 32) v = in_w[r*HDIM + c];
  else if(r < 48) v = ew[(r-32)*HDIM + c];
  else if(r == 48) v = eb[c];
  wcat[idx] = v;
}

// ---------------- prepack conv2_w: transpose + bf16 hi/lo split ----------------
__global__ void k_w2b(const float* __restrict__ W, unsigned short* __restrict__ hi_,
                      unsigned short* __restrict__ lo_){
  int idx = blockIdx.x*256 + threadIdx.x;   // 6*65536
  int i = idx >> 16, r = idx & 65535;
  int n = r >> 8, k = r & 255;
  float v = W[((size_t)i*256 + k)*256 + n];
  unsigned short h = f2bf(v);
  float lo = v - bf2f(h);
  hi_[((size_t)i*256 + n)*256 + k] = h;
  lo_[((size_t)i*256 + n)*256 + k] = f2bf(lo);
}

// ---------------- init aggregation ----------------
__global__ __launch_bounds__(256) void k_init_agg(const float* __restrict__ node_x,
    const float* __restrict__ edge_e,
    const int* __restrict__ csr_off, const int* __restrict__ csr_src, const int* __restrict__ csr_eid,
    const float* __restrict__ no, const float* __restrict__ ni, const int* __restrict__ cnt_in,
    float* __restrict__ A48, int N){
  int v = blockIdx.x*4 + (threadIdx.x>>6);
  if(v >= N) return;
  int lane = threadIdx.x & 63;
  int beg = csr_off[v], end = csr_off[v+1];
  float acc = 0.f;
  for(int p=beg; p<end; p++){
    int s = csr_src[p]; int e = csr_eid[p];
    if(lane < 32)      acc += node_x[(size_t)s*32 + lane] * no[s];
    else if(lane < 48) acc += edge_e[(size_t)e*16 + (lane-32)];
  }
  int ci = cnt_in[v];
  float out;
  if(lane < 32)      out = acc * ni[v];
  else if(lane < 48) out = acc * (1.f/(float)max(ci,1));
  else if(lane == 48) out = (ci>0) ? 1.f : 0.f;
  else out = 0.f;
  A48[(size_t)v*64 + lane] = out;
}

// ---------------- per-layer gather -> bf16 hi/lo ----------------
__global__ __launch_bounds__(256) void k_gather_bf(const float* __restrict__ h,
   const int* __restrict__ csr_off, const int* __restrict__ csr_src,
   const float* __restrict__ no, const float* __restrict__ ni,
   unsigned short* __restrict__ ahi, unsigned short* __restrict__ alo, int N, int Npad){
  int v = blockIdx.x*4 + (threadIdx.x>>6);
  if(v >= Npad) return;
  int lane = threadIdx.x & 63;
  float4 acc = make_float4(0.f,0.f,0.f,0.f);
  if(v < N){
    int beg = csr_off[v], end = csr_off[v+1];
    for(int p=beg; p<end; p++){
      int s = csr_src[p];
      float w = no[s];
      float4 x = *(const float4*)&h[(size_t)s*HDIM + lane*4];
      acc.x += x.x*w; acc.y += x.y*w; acc.z += x.z*w; acc.w += x.w*w;
    }
    float sc = ni[v];
    acc.x*=sc; acc.y*=sc; acc.z*=sc; acc.w*=sc;
  }
  unsigned short h0 = f2bf(acc.x), h1 = f2bf(acc.y), h2 = f2bf(acc.z), h3 = f2bf(acc.w);
  ushort4 hv = make_ushort4(h0,h1,h2,h3);
  ushort4 lv = make_ushort4(f2bf(acc.x - bf2f(h0)), f2bf(acc.y - bf2f(h1)),
                            f2bf(acc.z - bf2f(h2)), f2bf(acc.w - bf2f(h3)));
  *(ushort4*)&ahi[(size_t)v*HDIM + lane*4] = hv;
  *(ushort4*)&alo[(size_t)v*HDIM + lane*4] = lv;
}

// ---------------- layer GEMM: bf16 MFMA 3-term hi/lo, LDS-staged A, fused epilogue ----------------
// LAST: instead of writing h, compute per-row dot with head_w and atomicAdd into gsum.
template<bool LAST>
__global__ __launch_bounds__(256) void k_layer_mfma(
    const unsigned short* __restrict__ Ahi, const unsigned short* __restrict__ Alo,
    const unsigned short* __restrict__ Bhi, const unsigned short* __restrict__ Blo,
    const float* __restrict__ bias, const float* __restrict__ lng, const float* __restrict__ lnb,
    const float* __restrict__ gamL, const float* __restrict__ betL,
    const int* __restrict__ n_index, float* __restrict__ h,
    const float* __restrict__ hw, float* __restrict__ gsum, int N){
  __shared__ __align__(16) unsigned short AsH[2][4096];  // [buf][row*64 + k], swizzled
  __shared__ __align__(16) unsigned short AsL[2][4096];
  __shared__ float2 part[4][64];
  __shared__ float dotp[4][64];
  const int tid = threadIdx.x;
  const int w = tid >> 6, l = tid & 63;
  const int half = l >> 5, lcol = l & 31;
  const int row0 = blockIdx.x * 64;
  const int colb = w * 64;

  auto stage = [&](int c, int b){
    const int swzk = ((l&7) ^ (l>>3)) << 3;
    #pragma unroll
    for(int i=0;i<2;i++){
      const int r = w*16 + i*8;
      const size_t src = (size_t)(row0 + r + (l>>3))*HDIM + c*64 + swzk;
      gload_lds16(&Ahi[src], &AsH[b][r*64]);
      gload_lds16(&Alo[src], &AsL[b][r*64]);
    }
  };

  f32x16 acc[2][2] = {};
  const size_t bb = (size_t)(colb + lcol)*HDIM + half*8;
  const int swz = (lcol & 7) << 4;

  stage(0, 0);
  short8v bh0 = *(const short8v*)&Bhi[bb];
  short8v bh1 = *(const short8v*)&Bhi[bb + 32*HDIM];
  short8v bl0 = *(const short8v*)&Blo[bb];
  short8v bl1 = *(const short8v*)&Blo[bb + 32*HDIM];
  __syncthreads();

  #pragma unroll
  for(int t=0; t<16; t++){
    const int c = t>>2, ks = t&3, b = c&1;
    if(ks==0 && c<3) stage(c+1, (c+1)&1);
    short8v nbh0, nbh1, nbl0, nbl1;
    if(t < 15){
      const int tn = t+1;
      const int ko = (tn>>2)*64 + (tn&3)*16;
      nbh0 = *(const short8v*)&Bhi[bb + ko];
      nbh1 = *(const short8v*)&Bhi[bb + 32*HDIM + ko];
      nbl0 = *(const short8v*)&Blo[bb + ko];
      nbl1 = *(const short8v*)&Blo[bb + 32*HDIM + ko];
    }
    const int kb = (ks*32 + half*16) ^ swz;
    const char* baseH = (const char*)AsH[b];
    const char* baseL = (const char*)AsL[b];
    short8v ah0 = *(const short8v*)(baseH + lcol*128 + kb);
    short8v ah1 = *(const short8v*)(baseH + (32+lcol)*128 + kb);
    short8v al0 = *(const short8v*)(baseL + lcol*128 + kb);
    short8v al1 = *(const short8v*)(baseL + (32+lcol)*128 + kb);

    acc[0][0] = __builtin_amdgcn_mfma_f32_32x32x16_bf16(ah0, bh0, acc[0][0], 0,0,0);
    acc[0][1] = __builtin_amdgcn_mfma_f32_32x32x16_bf16(ah0, bh1, acc[0][1], 0,0,0);
    acc[1][0] = __builtin_amdgcn_mfma_f32_32x32x16_bf16(ah1, bh0, acc[1][0], 0,0,0);
    acc[1][1] = __builtin_amdgcn_mfma_f32_32x32x16_bf16(ah1, bh1, acc[1][1], 0,0,0);
    acc[0][0] = __builtin_amdgcn_mfma_f32_32x32x16_bf16(ah0, bl0, acc[0][0], 0,0,0);
    acc[0][1] = __builtin_amdgcn_mfma_f32_32x32x16_bf16(ah0, bl1, acc[0][1], 0,0,0);
    acc[1][0] = __builtin_amdgcn_mfma_f32_32x32x16_bf16(ah1, bl0, acc[1][0], 0,0,0);
    acc[1][1] = __builtin_amdgcn_mfma_f32_32x32x16_bf16(ah1, bl1, acc[1][1], 0,0,0);
    acc[0][0] = __builtin_amdgcn_mfma_f32_32x32x16_bf16(al0, bh0, acc[0][0], 0,0,0);
    acc[0][1] = __builtin_amdgcn_mfma_f32_32x32x16_bf16(al0, bh1, acc[0][1], 0,0,0);
    acc[1][0] = __builtin_amdgcn_mfma_f32_32x32x16_bf16(al1, bh0, acc[1][0], 0,0,0);
    acc[1][1] = __builtin_amdgcn_mfma_f32_32x32x16_bf16(al1, bh1, acc[1][1], 0,0,0);

    bh0 = nbh0; bh1 = nbh1; bl0 = nbl0; bl1 = nbl1;
    if(ks==3 && t<15) __syncthreads();
  }

  // epilogue
  float bias_c[2], lng_c[2], lnb_c[2], hw_c[2];
  #pragma unroll
  for(int nt=0; nt<2; nt++){
    const int c = colb + nt*32 + lcol;
    bias_c[nt] = bias[c]; lng_c[nt] = lng[c]; lnb_c[nt] = lnb[c];
    if(LAST) hw_c[nt] = hw[c];
  }
  #pragma unroll
  for(int mt=0; mt<2; mt++){
    #pragma unroll
    for(int r=0; r<16; r++){
      float z0 = acc[mt][0][r] + bias_c[0];
      float z1 = acc[mt][1][r] + bias_c[1];
      acc[mt][0][r] = z0; acc[mt][1][r] = z1;
      float s = z0 + z1, q = z0*z0 + z1*z1;
      #pragma unroll
      for(int off=1; off<32; off<<=1){ s += __shfl_xor(s, off, 64); q += __shfl_xor(q, off, 64); }
      const int rl = (r&3) + 8*(r>>2) + 4*half;
      part[w][mt*32 + rl] = make_float2(s, q);
    }
  }
  __syncthreads();

  #pragma unroll
  for(int mt=0; mt<2; mt++){
    #pragma unroll
    for(int r=0; r<16; r++){
      const int rl = (r&3) + 8*(r>>2) + 4*half;
      const int slot = mt*32 + rl;
      float2 t0 = part[0][slot], t1 = part[1][slot], t2 = part[2][slot], t3 = part[3][slot];
      float mu = (t0.x+t1.x+t2.x+t3.x) * (1.f/256.f);
      float ex2 = (t0.y+t1.y+t2.y+t3.y) * (1.f/256.f);
      float rs = rsqrtf(fmaxf(ex2 - mu*mu, 0.f) + 1e-5f);
      const int grow = row0 + mt*32 + rl;
      const bool ok = grow < N;
      const int bidx = ok ? n_index[grow] : 0;
      const float* gp = gamL + (size_t)bidx*HDIM;
      const float* bp = betL + (size_t)bidx*HDIM;
      float rowdot = 0.f;
      #pragma unroll
      for(int nt=0; nt<2; nt++){
        const int c = colb + nt*32 + lcol;
        float z = acc[mt][nt][r];
        float zn = (z - mu)*rs*lng_c[nt] + lnb_c[nt];
        float f = zn*(1.f + gp[c]) + bp[c];
        float o = silu_(f);
        if(LAST){
          float hv = ok ? h[(size_t)grow*HDIM + c] : 0.f;
          rowdot += (o + hv) * hw_c[nt];
        } else {
          if(ok){
            float hv = h[(size_t)grow*HDIM + c];
            h[(size_t)grow*HDIM + c] = o + hv;
          }
        }
      }
      if(LAST){
        #pragma unroll
        for(int off=1; off<32; off<<=1) rowdot += __shfl_xor(rowdot, off, 64);
        if(lcol == 0) dotp[w][mt*32 + rl] = rowdot;
      }
    }
  }
  if(LAST){
    __syncthreads();
    if(tid < 64){
      float s = dotp[0][tid] + dotp[1][tid] + dotp[2][tid] + dotp[3][tid];
      int row = row0 + tid;
      if(row < N) atomicAdd(&gsum[n_index[row]], s);
    }
  }
}

__global__ void k_final(const float* __restrict__ gsum, const int* __restrict__ gcnt,
                        const float* __restrict__ hb, float* __restrict__ out, int B){
  int b = blockIdx.x*256 + threadIdx.x;
  if(b < B) out[b] = gsum[b] / (float)max(gcnt[b],1) + hb[0];
}

extern "C" void kernel_launch(void* const* d_in, const int* in_sizes, int n_in,
                              void* d_out, int out_size, void* d_ws, size_t ws_size,
                              hipStream_t stream){
  const float* node_x   = (const float*)d_in[0];
  const float* edge_e   = (const float*)d_in[1];
  const float* t        = (const float*)d_in[2];
  const int*   n_index  = (const int*)d_in[3];
  const int*   src      = (const int*)d_in[4];
  const int*   dst      = (const int*)d_in[5];
  const float* in_conv_w= (const float*)d_in[6];
  const float* in_conv_b= (const float*)d_in[7];
  const float* edge_w   = (const float*)d_in[8];
  const float* edge_b   = (const float*)d_in[9];
  const float* t_w1     = (const float*)d_in[10];
  const float* t_b1     = (const float*)d_in[11];
  const float* t_w2     = (const float*)d_in[12];
  const float* t_b2     = (const float*)d_in[13];
  const float* conv2_w  = (const float*)d_in[16];
  const float* conv2_b  = (const float*)d_in[17];
  const float* ln2_g    = (const float*)d_in[20];
  const float* ln2_b    = (const float*)d_in[21];
  const float* film2_w  = (const float*)d_in[24];
  const float* film2_b  = (const float*)d_in[25];
  const float* head_w   = (const float*)d_in[26];
  const float* head_b   = (const float*)d_in[27];

  const int N = in_sizes[3];
  const int E = in_sizes[4];
  const int B = in_sizes[2];
  const int Npad = (N + 63) & ~63;

  char* w = (char*)d_ws;
  auto alloc = [&](size_t bytes)->char*{
    char* p = w; w += (bytes + 255) & ~(size_t)255; return p;
  };
  int*   cnt_out = (int*)  alloc((size_t)N*4);
  int*   cnt_in  = (int*)  alloc((size_t)N*4);
  float* no      = (float*)alloc((size_t)N*4);
  float* ni      = (float*)alloc((size_t)N*4);
  int*   csr_off = (int*)  alloc((size_t)(N+1)*4);
  int*   csr_pos = (int*)  alloc((size_t)N*4);
  int*   csr_src = (int*)  alloc((size_t)E*4);
  int*   csr_eid = (int*)  alloc((size_t)E*4);
  int*   partial = (int*)  alloc((size_t)256*4);
  float* cond    = (float*)alloc((size_t)B*HDIM*4);
  float* gbX     = (float*)alloc((size_t)12*B*HDIM*4);
  float* gsum    = (float*)alloc((size_t)B*4);
  int*   gcnt    = (int*)  alloc((size_t)B*4);
  float* h       = (float*)alloc((size_t)N*HDIM*4);
  unsigned short* agg_hi = (unsigned short*)alloc((size_t)Npad*HDIM*2);
  unsigned short* agg_lo = (unsigned short*)alloc((size_t)Npad*HDIM*2);
  unsigned short* Wthi   = (unsigned short*)alloc((size_t)NLAYERS*HDIM*HDIM*2);
  unsigned short* Wtlo   = (unsigned short*)alloc((size_t)NLAYERS*HDIM*HDIM*2);
  float* wcat    = (float*)alloc((size_t)64*HDIM*4);
  float* A48     = (float*)agg_hi;

  hipMemsetAsync(cnt_out, 0, (size_t)N*4, stream);
  hipMemsetAsync(cnt_in,  0, (size_t)N*4, stream);
  hipMemsetAsync(gsum,    0, (size_t)B*4, stream);
  hipMemsetAsync(gcnt,    0, (size_t)B*4, stream);

  int gE = (E+255)/256, gN = (N+255)/256;
  int nb1 = (N+1023)/1024;
  k_count<<<gE,256,0,stream>>>(src, dst, E, cnt_out, cnt_in);
  k_scan1<<<nb1,256,0,stream>>>(cnt_in, partial, N);
  k_scan2<<<1,256,0,stream>>>(partial, csr_off, nb1, N);
  k_scan3<<<nb1,256,0,stream>>>(cnt_in, partial, csr_off, N);
  k_prep<<<gN,256,0,stream>>>(cnt_out, cnt_in, csr_off, n_index, no, ni, csr_pos, gcnt, N);
  k_fill<<<gE,256,0,stream>>>(src, dst, E, csr_pos, csr_src, csr_eid);

  k_cond<<<B,256,0,stream>>>(t, t_w1, t_b1, t_w2, t_b2, cond);
  k_gemm_f32<256><<<dim3(B/64,12),256,0,stream>>>(cond, HDIM, film2_w, 512, film2_b,
                                                  gbX, HDIM, B, 1);

  k_w2b<<<NLAYERS*HDIM*HDIM/256,256,0,stream>>>(conv2_w, Wthi, Wtlo);
  k_wcat<<<64,256,0,stream>>>(in_conv_w, edge_w, edge_b, wcat);
  k_init_agg<<<(N+3)/4,256,0,stream>>>(node_x, edge_e, csr_off, csr_src, csr_eid,
                                       no, ni, cnt_in, A48, N);
  k_gemm_f32<64><<<Npad/64,256,0,stream>>>(A48, 64, wcat, HDIM, in_conv_b, h, HDIM, N, 0);

  for(int i=0;i<NLAYERS;i++){
    k_gather_bf<<<Npad/4,256,0,stream>>>(h, csr_off, csr_src, no, ni, agg_hi, agg_lo, N, Npad);
    if(i < NLAYERS-1)
      k_layer_mfma<false><<<Npad/64,256,0,stream>>>(agg_hi, agg_lo,
          Wthi + (size_t)i*HDIM*HDIM, Wtlo + (size_t)i*HDIM*HDIM,
          conv2_b + (size_t)i*HDIM,
          ln2_g + (size_t)i*HDIM, ln2_b + (size_t)i*HDIM,
          gbX + (size_t)(2*i)*B*HDIM, gbX + (size_t)(2*i+1)*B*HDIM,
          n_index, h, head_w, gsum, N);
    else
      k_layer_mfma<true><<<Npad/64,256,0,stream>>>(agg_hi, agg_lo,
          Wthi + (size_t)i*HDIM*HDIM, Wtlo + (size_t)i*HDIM*HDIM,
          conv2_b + (size_t)i*HDIM,
          ln2_g + (size_t)i*HDIM, ln2_b + (size_t)i*HDIM,
          gbX + (size_t)(2*i)*B*HDIM, gbX + (size_t)(2*i+1)*B*HDIM,
          n_index, h, head_w, gsum, N);
  }

  k_final<<<(B+255)/256,256,0,stream>>>(gsum, gcnt, head_b, (float*)d_out, B);
}

// Round 5
// 1807.818 us; speedup vs baseline: 1.5281x; 1.0325x over previous
//
#include <hip/hip_runtime.h>
#include <math.h>

#define HDIM 256
#define NLAYERS 6

typedef __attribute__((ext_vector_type(8))) short short8v;
typedef __attribute__((ext_vector_type(16))) float f32x16;

__device__ __forceinline__ float silu_(float x){ return x * (1.f/(1.f+__expf(-x))); }

__device__ __forceinline__ unsigned short f2bf(float f){
  unsigned u = __float_as_uint(f);
  u += 0x7FFF + ((u>>16)&1);
  return (unsigned short)(u>>16);
}
__device__ __forceinline__ float bf2f(unsigned short b){ return __uint_as_float(((unsigned)b)<<16); }

__device__ __forceinline__ void gload_lds16(const void* g, void* l){
  __builtin_amdgcn_global_load_lds((const __attribute__((address_space(1))) void*)g,
                                   (__attribute__((address_space(3))) void*)l, 16, 0, 0);
}

// ---------------- degree counting ----------------
__global__ void k_count(const int* __restrict__ src, const int* __restrict__ dst, int E,
                        int* __restrict__ cnt_out, int* __restrict__ cnt_in){
  int e = blockIdx.x*256 + threadIdx.x;
  if(e < E){
    atomicAdd(&cnt_out[src[e]], 1);
    atomicAdd(&cnt_in[dst[e]], 1);
  }
}

// ---------------- multi-block exclusive scan of cnt_in -> csr_off ----------------
__global__ __launch_bounds__(256) void k_scan1(const int* __restrict__ cnt_in,
                                               int* __restrict__ partial, int N){
  __shared__ int s[256];
  int b = blockIdx.x, tid = threadIdx.x;
  int i0 = b*1024 + tid*4;
  int sum = 0;
  #pragma unroll
  for(int j=0;j<4;j++){ int i=i0+j; if(i<N) sum += cnt_in[i]; }
  s[tid] = sum; __syncthreads();
  for(int off=128; off; off>>=1){ if(tid<off) s[tid]+=s[tid+off]; __syncthreads(); }
  if(tid==0) partial[b] = s[0];
}
__global__ __launch_bounds__(256) void k_scan2(int* __restrict__ partial,
                                               int* __restrict__ csr_off, int nb, int N){
  __shared__ int s[256];
  int tid = threadIdx.x;
  int v = (tid<nb) ? partial[tid] : 0;
  s[tid] = v; __syncthreads();
  for(int off=1; off<256; off<<=1){
    int t = (tid>=off) ? s[tid-off] : 0;
    __syncthreads(); s[tid] += t; __syncthreads();
  }
  if(tid<nb) partial[tid] = s[tid] - v;
  if(tid==255) csr_off[N] = s[255];
}
__global__ __launch_bounds__(256) void k_scan3(const int* __restrict__ cnt_in,
                                               const int* __restrict__ partial,
                                               int* __restrict__ csr_off, int N){
  __shared__ int s[256];
  int b = blockIdx.x, tid = threadIdx.x;
  int i0 = b*1024 + tid*4;
  int c[4];
  #pragma unroll
  for(int j=0;j<4;j++){ int i=i0+j; c[j] = (i<N) ? cnt_in[i] : 0; }
  int tot = c[0]+c[1]+c[2]+c[3];
  s[tid] = tot; __syncthreads();
  for(int off=1; off<256; off<<=1){
    int t = (tid>=off) ? s[tid-off] : 0;
    __syncthreads(); s[tid] += t; __syncthreads();
  }
  int run = s[tid] - tot + partial[b];
  #pragma unroll
  for(int j=0;j<4;j++){
    int i = i0+j;
    if(i<N) csr_off[i] = run;
    run += c[j];
  }
}

// ---------------- norms + csr fill pointer + per-graph node count ----------------
__global__ void k_prep(const int* __restrict__ cnt_out, const int* __restrict__ cnt_in,
                       const int* __restrict__ csr_off, const int* __restrict__ n_index,
                       float* __restrict__ no, float* __restrict__ ni,
                       int* __restrict__ csr_pos, int* __restrict__ gcnt, int N){
  int v = blockIdx.x*256 + threadIdx.x;
  if(v < N){
    no[v] = rsqrtf((float)max(cnt_out[v],1));
    ni[v] = rsqrtf((float)max(cnt_in[v],1));
    csr_pos[v] = csr_off[v];
    atomicAdd(&gcnt[n_index[v]], 1);
  }
}

__global__ void k_fill(const int* __restrict__ src, const int* __restrict__ dst, int E,
                       int* __restrict__ csr_pos, int* __restrict__ csr_src,
                       int* __restrict__ csr_eid){
  int e = blockIdx.x*256 + threadIdx.x;
  if(e < E){
    int p = atomicAdd(&csr_pos[dst[e]], 1);
    csr_src[p] = src[e];
    csr_eid[p] = e;
  }
}

// ---------------- time embedding + MLP -> cond ----------------
__global__ __launch_bounds__(256) void k_cond(const float* __restrict__ t,
        const float* __restrict__ w1, const float* __restrict__ b1,
        const float* __restrict__ w2, const float* __restrict__ b2,
        float* __restrict__ cond){
  __shared__ float emb[128];
  __shared__ float hid[256];
  int b = blockIdx.x, tid = threadIdx.x;
  float tv = t[b] * 1000.f;
  if(tid < 128){
    int k = tid & 63;
    float fr = expf(-logf(1000.f) * (float)k * (1.f/64.f));
    float a = tv * fr;
    emb[tid] = (tid < 64) ? sinf(a) : cosf(a);
  }
  __syncthreads();
  {
    float s = b1[tid];
    for(int k=0;k<128;k++) s += emb[k] * w1[k*HDIM + tid];
    hid[tid] = silu_(s);
  }
  __syncthreads();
  {
    float s = b2[tid];
    for(int k=0;k<256;k++) s += hid[k] * w2[k*HDIM + tid];
    cond[(size_t)b*HDIM + tid] = s;
  }
}

// ---------------- generic f32 tiled GEMM: 64 rows x 256 cols per block ----------------
template<int K>
__global__ __launch_bounds__(256) void k_gemm_f32(
    const float* __restrict__ A, int lda,
    const float* __restrict__ W, int ldw,
    const float* __restrict__ bias,
    float* __restrict__ out, int ldo, int M, int mode){
  if(mode == 1){
    int c = blockIdx.y;
    W    += (size_t)(c>>1)*131072 + (size_t)(c&1)*256;
    bias += (size_t)(c>>1)*512 + (size_t)(c&1)*256;
    out  += (size_t)c*1024*256;
  }
  __shared__ float As[64][36];
  __shared__ float Ws[32][256];
  const int tid = threadIdx.x;
  const int rg = tid >> 4;
  const int cg = tid & 15;
  const int row0 = blockIdx.x * 64;

  float4 acc[4][4];
  #pragma unroll
  for(int i=0;i<4;i++)
    #pragma unroll
    for(int m=0;m<4;m++) acc[i][m] = make_float4(0.f,0.f,0.f,0.f);

  const int ar = tid >> 2;
  const int ac = (tid & 3) * 8;
  const int wr = tid >> 3;
  const int wc = (tid & 7) * 32;

  for(int kk=0; kk<K; kk+=32){
    {
      int gr = row0 + ar;
      float4 v0 = make_float4(0.f,0.f,0.f,0.f), v1 = v0;
      if(gr < M){
        v0 = *(const float4*)&A[(size_t)gr*lda + kk + ac];
        v1 = *(const float4*)&A[(size_t)gr*lda + kk + ac + 4];
      }
      *(float4*)&As[ar][ac]   = v0;
      *(float4*)&As[ar][ac+4] = v1;
    }
    #pragma unroll
    for(int u=0;u<8;u++)
      *(float4*)&Ws[wr][wc + u*4] = *(const float4*)&W[(size_t)(kk+wr)*ldw + wc + u*4];
    __syncthreads();
    #pragma unroll 8
    for(int k=0;k<32;k++){
      float a0 = As[rg*4+0][k];
      float a1 = As[rg*4+1][k];
      float a2 = As[rg*4+2][k];
      float a3 = As[rg*4+3][k];
      #pragma unroll
      for(int m=0;m<4;m++){
        float4 w = *(const float4*)&Ws[k][cg*4 + m*64];
        acc[0][m].x += a0*w.x; acc[0][m].y += a0*w.y; acc[0][m].z += a0*w.z; acc[0][m].w += a0*w.w;
        acc[1][m].x += a1*w.x; acc[1][m].y += a1*w.y; acc[1][m].z += a1*w.z; acc[1][m].w += a1*w.w;
        acc[2][m].x += a2*w.x; acc[2][m].y += a2*w.y; acc[2][m].z += a2*w.z; acc[2][m].w += a2*w.w;
        acc[3][m].x += a3*w.x; acc[3][m].y += a3*w.y; acc[3][m].z += a3*w.z; acc[3][m].w += a3*w.w;
      }
    }
    __syncthreads();
  }

  const int c0 = cg * 4;
  #pragma unroll
  for(int i=0;i<4;i++){
    const int gr = row0 + rg*4 + i;
    if(gr >= M) continue;
    #pragma unroll
    for(int m=0;m<4;m++){
      const int c = c0 + m*64;
      float4 b4 = *(const float4*)&bias[c];
      float4 o = make_float4(acc[i][m].x+b4.x, acc[i][m].y+b4.y,
                             acc[i][m].z+b4.z, acc[i][m].w+b4.w);
      *(float4*)&out[(size_t)gr*ldo + c] = o;
    }
  }
}

// ---------------- build stacked init weight [64][256] ----------------
__global__ void k_wcat(const float* __restrict__ in_w, const float* __restrict__ ew,
                       const float* __restrict__ eb, float* __restrict__ wcat){
  int idx = blockIdx.x*256 + threadIdx.x;
  int r = idx>>8, c = idx&255;
  float v = 0.f;
  if(r < 32) v = in_w[r*HDIM + c];
  else if(r < 48) v = ew[(r-32)*HDIM + c];
  else if(r == 48) v = eb[c];
  wcat[idx] = v;
}

// ---------------- prepack conv2_w: transpose + bf16 hi/lo split ----------------
__global__ void k_w2b(const float* __restrict__ W, unsigned short* __restrict__ hi_,
                      unsigned short* __restrict__ lo_){
  int idx = blockIdx.x*256 + threadIdx.x;   // 6*65536
  int i = idx >> 16, r = idx & 65535;
  int n = r >> 8, k = r & 255;
  float v = W[((size_t)i*256 + k)*256 + n];
  unsigned short h = f2bf(v);
  float lo = v - bf2f(h);
  hi_[((size_t)i*256 + n)*256 + k] = h;
  lo_[((size_t)i*256 + n)*256 + k] = f2bf(lo);
}

// ---------------- init aggregation ----------------
__global__ __launch_bounds__(256) void k_init_agg(const float* __restrict__ node_x,
    const float* __restrict__ edge_e,
    const int* __restrict__ csr_off, const int* __restrict__ csr_src, const int* __restrict__ csr_eid,
    const float* __restrict__ no, const float* __restrict__ ni, const int* __restrict__ cnt_in,
    float* __restrict__ A48, int N){
  int v = blockIdx.x*4 + (threadIdx.x>>6);
  if(v >= N) return;
  int lane = threadIdx.x & 63;
  int beg = csr_off[v], end = csr_off[v+1];
  float acc = 0.f;
  for(int p=beg; p<end; p++){
    int s = csr_src[p]; int e = csr_eid[p];
    if(lane < 32)      acc += node_x[(size_t)s*32 + lane] * no[s];
    else if(lane < 48) acc += edge_e[(size_t)e*16 + (lane-32)];
  }
  int ci = cnt_in[v];
  float out;
  if(lane < 32)      out = acc * ni[v];
  else if(lane < 48) out = acc * (1.f/(float)max(ci,1));
  else if(lane == 48) out = (ci>0) ? 1.f : 0.f;
  else out = 0.f;
  A48[(size_t)v*64 + lane] = out;
}

// ---------------- per-layer gather -> bf16 hi/lo ----------------
__global__ __launch_bounds__(256) void k_gather_bf(const float* __restrict__ h,
   const int* __restrict__ csr_off, const int* __restrict__ csr_src,
   const float* __restrict__ no, const float* __restrict__ ni,
   unsigned short* __restrict__ ahi, unsigned short* __restrict__ alo, int N, int Npad){
  int v = blockIdx.x*4 + (threadIdx.x>>6);
  if(v >= Npad) return;
  int lane = threadIdx.x & 63;
  float4 acc = make_float4(0.f,0.f,0.f,0.f);
  if(v < N){
    int beg = csr_off[v], end = csr_off[v+1];
    for(int p=beg; p<end; p++){
      int s = csr_src[p];
      float w = no[s];
      float4 x = *(const float4*)&h[(size_t)s*HDIM + lane*4];
      acc.x += x.x*w; acc.y += x.y*w; acc.z += x.z*w; acc.w += x.w*w;
    }
    float sc = ni[v];
    acc.x*=sc; acc.y*=sc; acc.z*=sc; acc.w*=sc;
  }
  unsigned short h0 = f2bf(acc.x), h1 = f2bf(acc.y), h2 = f2bf(acc.z), h3 = f2bf(acc.w);
  ushort4 hv = make_ushort4(h0,h1,h2,h3);
  ushort4 lv = make_ushort4(f2bf(acc.x - bf2f(h0)), f2bf(acc.y - bf2f(h1)),
                            f2bf(acc.z - bf2f(h2)), f2bf(acc.w - bf2f(h3)));
  *(ushort4*)&ahi[(size_t)v*HDIM + lane*4] = hv;
  *(ushort4*)&alo[(size_t)v*HDIM + lane*4] = lv;
}

// ---------------- layer GEMM v3: whole A-tile in LDS, barrier-free MFMA loop ----------------
// block = 256 thr = 4 waves; tile 64 rows x 256 cols; wave tile 64x64 (2x2 of 32x32)
// A (hi+lo, 64KB) staged ONCE via global_load_lds with 16B-slot XOR swizzle; single barrier;
// fully-unrolled 16-iter MFMA loop with 4-slot rotating B prefetch issued 3 ahead.
template<bool LAST>
__global__ __launch_bounds__(256, 2) void k_layer_mfma(
    const unsigned short* __restrict__ Ahi, const unsigned short* __restrict__ Alo,
    const unsigned short* __restrict__ Bhi, const unsigned short* __restrict__ Blo,
    const float* __restrict__ bias, const float* __restrict__ lng, const float* __restrict__ lnb,
    const float* __restrict__ gamL, const float* __restrict__ betL,
    const int* __restrict__ n_index, float* __restrict__ h,
    const float* __restrict__ hw, float* __restrict__ gsum, int N){
  __shared__ __align__(16) unsigned short AsH[16384];  // 64 rows x 256 k, swizzled 16B slots
  __shared__ __align__(16) unsigned short AsL[16384];
  __shared__ float2 part[4][64];
  __shared__ float dotp[4][64];
  const int tid = threadIdx.x;
  const int w = tid >> 6, l = tid & 63;
  const int half = l >> 5, lcol = l & 31;
  const int row0 = blockIdx.x * 64;
  const int colb = w * 64;

  const size_t bb = (size_t)(colb + lcol)*HDIM + half*8;

  // B prefetch: 4 rotating slots, issue 3 ahead
  short8v Bh0[4], Bh1[4], Bl0[4], Bl1[4];
  #define LOADB(t, s) { \
    Bh0[s] = *(const short8v*)&Bhi[bb + (t)*16]; \
    Bh1[s] = *(const short8v*)&Bhi[bb + 32*HDIM + (t)*16]; \
    Bl0[s] = *(const short8v*)&Blo[bb + (t)*16]; \
    Bl1[s] = *(const short8v*)&Blo[bb + 32*HDIM + (t)*16]; }
  LOADB(0,0) LOADB(1,1) LOADB(2,2)

  // stage entire A tile (hi + lo): thread tid covers LDS 16B slot tid of 8 chunks
  {
    const int m = tid & 31;          // 16B slot within row
    const int rofs = tid >> 5;       // 0..7
    #pragma unroll
    for(int chunk=0; chunk<8; chunk++){
      const int row = chunk*8 + rofs;
      const int msw = (m & 24) | ((m ^ row) & 7);           // inverse-swizzled source slot
      const size_t src = (size_t)(row0 + row)*HDIM + msw*8; // element offset
      gload_lds16(&Ahi[src], (char*)AsH + chunk*4096 + tid*16);
      gload_lds16(&Alo[src], (char*)AsL + chunk*4096 + tid*16);
    }
  }
  __syncthreads();   // single drain: all A staged, B0..B2 in flight/done

  f32x16 acc[2][2] = {};
  const char* baseH = (const char*)AsH;
  const char* baseL = (const char*)AsL;

  #pragma unroll
  for(int t=0; t<16; t++){
    if(t < 13) LOADB(t+3, (t+3)&3)
    const int s = t & 3;
    const int g = t*2 + half;                         // global 16B slot in row
    const int slot = (g & 24) | ((g ^ lcol) & 7);     // swizzled LDS slot
    short8v ah0 = *(const short8v*)(baseH + lcol*512 + slot*16);
    short8v ah1 = *(const short8v*)(baseH + (32+lcol)*512 + slot*16);
    short8v al0 = *(const short8v*)(baseL + lcol*512 + slot*16);
    short8v al1 = *(const short8v*)(baseL + (32+lcol)*512 + slot*16);

    acc[0][0] = __builtin_amdgcn_mfma_f32_32x32x16_bf16(ah0, Bh0[s], acc[0][0], 0,0,0);
    acc[0][1] = __builtin_amdgcn_mfma_f32_32x32x16_bf16(ah0, Bh1[s], acc[0][1], 0,0,0);
    acc[1][0] = __builtin_amdgcn_mfma_f32_32x32x16_bf16(ah1, Bh0[s], acc[1][0], 0,0,0);
    acc[1][1] = __builtin_amdgcn_mfma_f32_32x32x16_bf16(ah1, Bh1[s], acc[1][1], 0,0,0);
    acc[0][0] = __builtin_amdgcn_mfma_f32_32x32x16_bf16(ah0, Bl0[s], acc[0][0], 0,0,0);
    acc[0][1] = __builtin_amdgcn_mfma_f32_32x32x16_bf16(ah0, Bl1[s], acc[0][1], 0,0,0);
    acc[1][0] = __builtin_amdgcn_mfma_f32_32x32x16_bf16(ah1, Bl0[s], acc[1][0], 0,0,0);
    acc[1][1] = __builtin_amdgcn_mfma_f32_32x32x16_bf16(ah1, Bl1[s], acc[1][1], 0,0,0);
    acc[0][0] = __builtin_amdgcn_mfma_f32_32x32x16_bf16(al0, Bh0[s], acc[0][0], 0,0,0);
    acc[0][1] = __builtin_amdgcn_mfma_f32_32x32x16_bf16(al0, Bh1[s], acc[0][1], 0,0,0);
    acc[1][0] = __builtin_amdgcn_mfma_f32_32x32x16_bf16(al1, Bh0[s], acc[1][0], 0,0,0);
    acc[1][1] = __builtin_amdgcn_mfma_f32_32x32x16_bf16(al1, Bh1[s], acc[1][1], 0,0,0);
  }
  #undef LOADB

  // epilogue: bias, LN stats, FiLM, SiLU, residual (or head dot for LAST)
  float bias_c[2], lng_c[2], lnb_c[2], hw_c[2];
  #pragma unroll
  for(int nt=0; nt<2; nt++){
    const int c = colb + nt*32 + lcol;
    bias_c[nt] = bias[c]; lng_c[nt] = lng[c]; lnb_c[nt] = lnb[c];
    if(LAST) hw_c[nt] = hw[c];
  }
  #pragma unroll
  for(int mt=0; mt<2; mt++){
    #pragma unroll
    for(int r=0; r<16; r++){
      float z0 = acc[mt][0][r] + bias_c[0];
      float z1 = acc[mt][1][r] + bias_c[1];
      acc[mt][0][r] = z0; acc[mt][1][r] = z1;
      float s = z0 + z1, q = z0*z0 + z1*z1;
      #pragma unroll
      for(int off=1; off<32; off<<=1){ s += __shfl_xor(s, off, 64); q += __shfl_xor(q, off, 64); }
      const int rl = (r&3) + 8*(r>>2) + 4*half;
      part[w][mt*32 + rl] = make_float2(s, q);
    }
  }
  // prefetch bidx for all 32 output rows before the barrier (overlaps barrier wait)
  int bidx_r[2][16];
  #pragma unroll
  for(int mt=0; mt<2; mt++){
    #pragma unroll
    for(int r=0; r<16; r++){
      const int rl = (r&3) + 8*(r>>2) + 4*half;
      const int grow = row0 + mt*32 + rl;
      bidx_r[mt][r] = (grow < N) ? n_index[grow] : 0;
    }
  }
  __syncthreads();

  #pragma unroll
  for(int mt=0; mt<2; mt++){
    #pragma unroll
    for(int r=0; r<16; r++){
      const int rl = (r&3) + 8*(r>>2) + 4*half;
      const int slot = mt*32 + rl;
      float2 t0 = part[0][slot], t1 = part[1][slot], t2 = part[2][slot], t3 = part[3][slot];
      float mu = (t0.x+t1.x+t2.x+t3.x) * (1.f/256.f);
      float ex2 = (t0.y+t1.y+t2.y+t3.y) * (1.f/256.f);
      float rs = rsqrtf(fmaxf(ex2 - mu*mu, 0.f) + 1e-5f);
      const int grow = row0 + mt*32 + rl;
      const bool ok = grow < N;
      const int bidx = bidx_r[mt][r];
      const float* gp = gamL + (size_t)bidx*HDIM;
      const float* bp = betL + (size_t)bidx*HDIM;
      float rowdot = 0.f;
      #pragma unroll
      for(int nt=0; nt<2; nt++){
        const int c = colb + nt*32 + lcol;
        float z = acc[mt][nt][r];
        float zn = (z - mu)*rs*lng_c[nt] + lnb_c[nt];
        float f = zn*(1.f + gp[c]) + bp[c];
        float o = silu_(f);
        if(LAST){
          float hv = ok ? h[(size_t)grow*HDIM + c] : 0.f;
          rowdot += (o + hv) * hw_c[nt];
        } else {
          if(ok){
            float hv = h[(size_t)grow*HDIM + c];
            h[(size_t)grow*HDIM + c] = o + hv;
          }
        }
      }
      if(LAST){
        #pragma unroll
        for(int off=1; off<32; off<<=1) rowdot += __shfl_xor(rowdot, off, 64);
        if(lcol == 0) dotp[w][mt*32 + rl] = rowdot;
      }
    }
  }
  if(LAST){
    __syncthreads();
    if(tid < 64){
      float s = dotp[0][tid] + dotp[1][tid] + dotp[2][tid] + dotp[3][tid];
      int row = row0 + tid;
      if(row < N) atomicAdd(&gsum[n_index[row]], s);
    }
  }
}

__global__ void k_final(const float* __restrict__ gsum, const int* __restrict__ gcnt,
                        const float* __restrict__ hb, float* __restrict__ out, int B){
  int b = blockIdx.x*256 + threadIdx.x;
  if(b < B) out[b] = gsum[b] / (float)max(gcnt[b],1) + hb[0];
}

extern "C" void kernel_launch(void* const* d_in, const int* in_sizes, int n_in,
                              void* d_out, int out_size, void* d_ws, size_t ws_size,
                              hipStream_t stream){
  const float* node_x   = (const float*)d_in[0];
  const float* edge_e   = (const float*)d_in[1];
  const float* t        = (const float*)d_in[2];
  const int*   n_index  = (const int*)d_in[3];
  const int*   src      = (const int*)d_in[4];
  const int*   dst      = (const int*)d_in[5];
  const float* in_conv_w= (const float*)d_in[6];
  const float* in_conv_b= (const float*)d_in[7];
  const float* edge_w   = (const float*)d_in[8];
  const float* edge_b   = (const float*)d_in[9];
  const float* t_w1     = (const float*)d_in[10];
  const float* t_b1     = (const float*)d_in[11];
  const float* t_w2     = (const float*)d_in[12];
  const float* t_b2     = (const float*)d_in[13];
  const float* conv2_w  = (const float*)d_in[16];
  const float* conv2_b  = (const float*)d_in[17];
  const float* ln2_g    = (const float*)d_in[20];
  const float* ln2_b    = (const float*)d_in[21];
  const float* film2_w  = (const float*)d_in[24];
  const float* film2_b  = (const float*)d_in[25];
  const float* head_w   = (const float*)d_in[26];
  const float* head_b   = (const float*)d_in[27];

  const int N = in_sizes[3];
  const int E = in_sizes[4];
  const int B = in_sizes[2];
  const int Npad = (N + 63) & ~63;

  char* w = (char*)d_ws;
  auto alloc = [&](size_t bytes)->char*{
    char* p = w; w += (bytes + 255) & ~(size_t)255; return p;
  };
  int*   cnt_out = (int*)  alloc((size_t)N*4);
  int*   cnt_in  = (int*)  alloc((size_t)N*4);
  float* no      = (float*)alloc((size_t)N*4);
  float* ni      = (float*)alloc((size_t)N*4);
  int*   csr_off = (int*)  alloc((size_t)(N+1)*4);
  int*   csr_pos = (int*)  alloc((size_t)N*4);
  int*   csr_src = (int*)  alloc((size_t)E*4);
  int*   csr_eid = (int*)  alloc((size_t)E*4);
  int*   partial = (int*)  alloc((size_t)256*4);
  float* cond    = (float*)alloc((size_t)B*HDIM*4);
  float* gbX     = (float*)alloc((size_t)12*B*HDIM*4);
  float* gsum    = (float*)alloc((size_t)B*4);
  int*   gcnt    = (int*)  alloc((size_t)B*4);
  float* h       = (float*)alloc((size_t)N*HDIM*4);
  unsigned short* agg_hi = (unsigned short*)alloc((size_t)Npad*HDIM*2);
  unsigned short* agg_lo = (unsigned short*)alloc((size_t)Npad*HDIM*2);
  unsigned short* Wthi   = (unsigned short*)alloc((size_t)NLAYERS*HDIM*HDIM*2);
  unsigned short* Wtlo   = (unsigned short*)alloc((size_t)NLAYERS*HDIM*HDIM*2);
  float* wcat    = (float*)alloc((size_t)64*HDIM*4);
  float* A48     = (float*)agg_hi;

  hipMemsetAsync(cnt_out, 0, (size_t)N*4, stream);
  hipMemsetAsync(cnt_in,  0, (size_t)N*4, stream);
  hipMemsetAsync(gsum,    0, (size_t)B*4, stream);
  hipMemsetAsync(gcnt,    0, (size_t)B*4, stream);

  int gE = (E+255)/256, gN = (N+255)/256;
  int nb1 = (N+1023)/1024;
  k_count<<<gE,256,0,stream>>>(src, dst, E, cnt_out, cnt_in);
  k_scan1<<<nb1,256,0,stream>>>(cnt_in, partial, N);
  k_scan2<<<1,256,0,stream>>>(partial, csr_off, nb1, N);
  k_scan3<<<nb1,256,0,stream>>>(cnt_in, partial, csr_off, N);
  k_prep<<<gN,256,0,stream>>>(cnt_out, cnt_in, csr_off, n_index, no, ni, csr_pos, gcnt, N);
  k_fill<<<gE,256,0,stream>>>(src, dst, E, csr_pos, csr_src, csr_eid);

  k_cond<<<B,256,0,stream>>>(t, t_w1, t_b1, t_w2, t_b2, cond);
  k_gemm_f32<256><<<dim3(B/64,12),256,0,stream>>>(cond, HDIM, film2_w, 512, film2_b,
                                                  gbX, HDIM, B, 1);

  k_w2b<<<NLAYERS*HDIM*HDIM/256,256,0,stream>>>(conv2_w, Wthi, Wtlo);
  k_wcat<<<64,256,0,stream>>>(in_conv_w, edge_w, edge_b, wcat);
  k_init_agg<<<(N+3)/4,256,0,stream>>>(node_x, edge_e, csr_off, csr_src, csr_eid,
                                       no, ni, cnt_in, A48, N);
  k_gemm_f32<64><<<Npad/64,256,0,stream>>>(A48, 64, wcat, HDIM, in_conv_b, h, HDIM, N, 0);

  for(int i=0;i<NLAYERS;i++){
    k_gather_bf<<<Npad/4,256,0,stream>>>(h, csr_off, csr_src, no, ni, agg_hi, agg_lo, N, Npad);
    if(i < NLAYERS-1)
      k_layer_mfma<false><<<Npad/64,256,0,stream>>>(agg_hi, agg_lo,
          Wthi + (size_t)i*HDIM*HDIM, Wtlo + (size_t)i*HDIM*HDIM,
          conv2_b + (size_t)i*HDIM,
          ln2_g + (size_t)i*HDIM, ln2_b + (size_t)i*HDIM,
          gbX + (size_t)(2*i)*B*HDIM, gbX + (size_t)(2*i+1)*B*HDIM,
          n_index, h, head_w, gsum, N);
    else
      k_layer_mfma<true><<<Npad/64,256,0,stream>>>(agg_hi, agg_lo,
          Wthi + (size_t)i*HDIM*HDIM, Wtlo + (size_t)i*HDIM*HDIM,
          conv2_b + (size_t)i*HDIM,
          ln2_g + (size_t)i*HDIM, ln2_b + (size_t)i*HDIM,
          gbX + (size_t)(2*i)*B*HDIM, gbX + (size_t)(2*i+1)*B*HDIM,
          n_index, h, head_w, gsum, N);
  }

  k_final<<<(B+255)/256,256,0,stream>>>(gsum, gcnt, head_b, (float*)d_out, B);
}

// Round 6
// 1504.738 us; speedup vs baseline: 1.8358x; 1.2014x over previous
//
#include <hip/hip_runtime.h>
#include <math.h>

#define HDIM 256
#define NLAYERS 6

typedef __attribute__((ext_vector_type(8))) short short8v;
typedef __attribute__((ext_vector_type(16))) float f32x16;

__device__ __forceinline__ float silu_(float x){ return x * (1.f/(1.f+__expf(-x))); }

__device__ __forceinline__ unsigned short f2bf(float f){
  unsigned u = __float_as_uint(f);
  u += 0x7FFF + ((u>>16)&1);
  return (unsigned short)(u>>16);
}
__device__ __forceinline__ float bf2f(unsigned short b){ return __uint_as_float(((unsigned)b)<<16); }

__device__ __forceinline__ void gload_lds16(const void* g, void* l){
  __builtin_amdgcn_global_load_lds((const __attribute__((address_space(1))) void*)g,
                                   (__attribute__((address_space(3))) void*)l, 16, 0, 0);
}

// ---------------- degree counting ----------------
__global__ void k_count(const int* __restrict__ src, const int* __restrict__ dst, int E,
                        int* __restrict__ cnt_out, int* __restrict__ cnt_in){
  int e = blockIdx.x*256 + threadIdx.x;
  if(e < E){
    atomicAdd(&cnt_out[src[e]], 1);
    atomicAdd(&cnt_in[dst[e]], 1);
  }
}

// ---------------- multi-block exclusive scan of cnt_in -> csr_off ----------------
__global__ __launch_bounds__(256) void k_scan1(const int* __restrict__ cnt_in,
                                               int* __restrict__ partial, int N){
  __shared__ int s[256];
  int b = blockIdx.x, tid = threadIdx.x;
  int i0 = b*1024 + tid*4;
  int sum = 0;
  #pragma unroll
  for(int j=0;j<4;j++){ int i=i0+j; if(i<N) sum += cnt_in[i]; }
  s[tid] = sum; __syncthreads();
  for(int off=128; off; off>>=1){ if(tid<off) s[tid]+=s[tid+off]; __syncthreads(); }
  if(tid==0) partial[b] = s[0];
}
__global__ __launch_bounds__(256) void k_scan2(int* __restrict__ partial,
                                               int* __restrict__ csr_off, int nb, int N){
  __shared__ int s[256];
  int tid = threadIdx.x;
  int v = (tid<nb) ? partial[tid] : 0;
  s[tid] = v; __syncthreads();
  for(int off=1; off<256; off<<=1){
    int t = (tid>=off) ? s[tid-off] : 0;
    __syncthreads(); s[tid] += t; __syncthreads();
  }
  if(tid<nb) partial[tid] = s[tid] - v;
  if(tid==255) csr_off[N] = s[255];
}
__global__ __launch_bounds__(256) void k_scan3(const int* __restrict__ cnt_in,
                                               const int* __restrict__ partial,
                                               int* __restrict__ csr_off, int N){
  __shared__ int s[256];
  int b = blockIdx.x, tid = threadIdx.x;
  int i0 = b*1024 + tid*4;
  int c[4];
  #pragma unroll
  for(int j=0;j<4;j++){ int i=i0+j; c[j] = (i<N) ? cnt_in[i] : 0; }
  int tot = c[0]+c[1]+c[2]+c[3];
  s[tid] = tot; __syncthreads();
  for(int off=1; off<256; off<<=1){
    int t = (tid>=off) ? s[tid-off] : 0;
    __syncthreads(); s[tid] += t; __syncthreads();
  }
  int run = s[tid] - tot + partial[b];
  #pragma unroll
  for(int j=0;j<4;j++){
    int i = i0+j;
    if(i<N) csr_off[i] = run;
    run += c[j];
  }
}

// ---------------- norms + csr fill pointer + per-graph node count ----------------
__global__ void k_prep(const int* __restrict__ cnt_out, const int* __restrict__ cnt_in,
                       const int* __restrict__ csr_off, const int* __restrict__ n_index,
                       float* __restrict__ no, float* __restrict__ ni,
                       int* __restrict__ csr_pos, int* __restrict__ gcnt, int N){
  int v = blockIdx.x*256 + threadIdx.x;
  if(v < N){
    no[v] = rsqrtf((float)max(cnt_out[v],1));
    ni[v] = rsqrtf((float)max(cnt_in[v],1));
    csr_pos[v] = csr_off[v];
    atomicAdd(&gcnt[n_index[v]], 1);
  }
}

__global__ void k_fill(const int* __restrict__ src, const int* __restrict__ dst, int E,
                       int* __restrict__ csr_pos, int* __restrict__ csr_src,
                       int* __restrict__ csr_eid){
  int e = blockIdx.x*256 + threadIdx.x;
  if(e < E){
    int p = atomicAdd(&csr_pos[dst[e]], 1);
    csr_src[p] = src[e];
    csr_eid[p] = e;
  }
}

// ---------------- time embedding + MLP -> cond ----------------
__global__ __launch_bounds__(256) void k_cond(const float* __restrict__ t,
        const float* __restrict__ w1, const float* __restrict__ b1,
        const float* __restrict__ w2, const float* __restrict__ b2,
        float* __restrict__ cond){
  __shared__ float emb[128];
  __shared__ float hid[256];
  int b = blockIdx.x, tid = threadIdx.x;
  float tv = t[b] * 1000.f;
  if(tid < 128){
    int k = tid & 63;
    float fr = expf(-logf(1000.f) * (float)k * (1.f/64.f));
    float a = tv * fr;
    emb[tid] = (tid < 64) ? sinf(a) : cosf(a);
  }
  __syncthreads();
  {
    float s = b1[tid];
    for(int k=0;k<128;k++) s += emb[k] * w1[k*HDIM + tid];
    hid[tid] = silu_(s);
  }
  __syncthreads();
  {
    float s = b2[tid];
    for(int k=0;k<256;k++) s += hid[k] * w2[k*HDIM + tid];
    cond[(size_t)b*HDIM + tid] = s;
  }
}

// ---------------- generic f32 tiled GEMM: 64 rows x 256 cols per block ----------------
template<int K>
__global__ __launch_bounds__(256) void k_gemm_f32(
    const float* __restrict__ A, int lda,
    const float* __restrict__ W, int ldw,
    const float* __restrict__ bias,
    float* __restrict__ out, int ldo, int M, int mode){
  if(mode == 1){
    int c = blockIdx.y;
    W    += (size_t)(c>>1)*131072 + (size_t)(c&1)*256;
    bias += (size_t)(c>>1)*512 + (size_t)(c&1)*256;
    out  += (size_t)c*1024*256;
  }
  __shared__ float As[64][36];
  __shared__ float Ws[32][256];
  const int tid = threadIdx.x;
  const int rg = tid >> 4;
  const int cg = tid & 15;
  const int row0 = blockIdx.x * 64;

  float4 acc[4][4];
  #pragma unroll
  for(int i=0;i<4;i++)
    #pragma unroll
    for(int m=0;m<4;m++) acc[i][m] = make_float4(0.f,0.f,0.f,0.f);

  const int ar = tid >> 2;
  const int ac = (tid & 3) * 8;
  const int wr = tid >> 3;
  const int wc = (tid & 7) * 32;

  for(int kk=0; kk<K; kk+=32){
    {
      int gr = row0 + ar;
      float4 v0 = make_float4(0.f,0.f,0.f,0.f), v1 = v0;
      if(gr < M){
        v0 = *(const float4*)&A[(size_t)gr*lda + kk + ac];
        v1 = *(const float4*)&A[(size_t)gr*lda + kk + ac + 4];
      }
      *(float4*)&As[ar][ac]   = v0;
      *(float4*)&As[ar][ac+4] = v1;
    }
    #pragma unroll
    for(int u=0;u<8;u++)
      *(float4*)&Ws[wr][wc + u*4] = *(const float4*)&W[(size_t)(kk+wr)*ldw + wc + u*4];
    __syncthreads();
    #pragma unroll 8
    for(int k=0;k<32;k++){
      float a0 = As[rg*4+0][k];
      float a1 = As[rg*4+1][k];
      float a2 = As[rg*4+2][k];
      float a3 = As[rg*4+3][k];
      #pragma unroll
      for(int m=0;m<4;m++){
        float4 w = *(const float4*)&Ws[k][cg*4 + m*64];
        acc[0][m].x += a0*w.x; acc[0][m].y += a0*w.y; acc[0][m].z += a0*w.z; acc[0][m].w += a0*w.w;
        acc[1][m].x += a1*w.x; acc[1][m].y += a1*w.y; acc[1][m].z += a1*w.z; acc[1][m].w += a1*w.w;
        acc[2][m].x += a2*w.x; acc[2][m].y += a2*w.y; acc[2][m].z += a2*w.z; acc[2][m].w += a2*w.w;
        acc[3][m].x += a3*w.x; acc[3][m].y += a3*w.y; acc[3][m].z += a3*w.z; acc[3][m].w += a3*w.w;
      }
    }
    __syncthreads();
  }

  const int c0 = cg * 4;
  #pragma unroll
  for(int i=0;i<4;i++){
    const int gr = row0 + rg*4 + i;
    if(gr >= M) continue;
    #pragma unroll
    for(int m=0;m<4;m++){
      const int c = c0 + m*64;
      float4 b4 = *(const float4*)&bias[c];
      float4 o = make_float4(acc[i][m].x+b4.x, acc[i][m].y+b4.y,
                             acc[i][m].z+b4.z, acc[i][m].w+b4.w);
      *(float4*)&out[(size_t)gr*ldo + c] = o;
    }
  }
}

// ---------------- build stacked init weight [64][256] ----------------
__global__ void k_wcat(const float* __restrict__ in_w, const float* __restrict__ ew,
                       const float* __restrict__ eb, float* __restrict__ wcat){
  int idx = blockIdx.x*256 + threadIdx.x;
  int r = idx>>8, c = idx&255;
  float v = 0.f;
  if(r < 32) v = in_w[r*HDIM + c];
  else if(r < 48) v = ew[(r-32)*HDIM + c];
  else if(r == 48) v = eb[c];
  wcat[idx] = v;
}

// ---------------- prepack conv2_w: transpose + bf16 hi/lo split ----------------
__global__ void k_w2b(const float* __restrict__ W, unsigned short* __restrict__ hi_,
                      unsigned short* __restrict__ lo_){
  int idx = blockIdx.x*256 + threadIdx.x;   // 6*65536
  int i = idx >> 16, r = idx & 65535;
  int n = r >> 8, k = r & 255;
  float v = W[((size_t)i*256 + k)*256 + n];
  unsigned short h = f2bf(v);
  float lo = v - bf2f(h);
  hi_[((size_t)i*256 + n)*256 + k] = h;
  lo_[((size_t)i*256 + n)*256 + k] = f2bf(lo);
}

// ---------------- init aggregation ----------------
__global__ __launch_bounds__(256) void k_init_agg(const float* __restrict__ node_x,
    const float* __restrict__ edge_e,
    const int* __restrict__ csr_off, const int* __restrict__ csr_src, const int* __restrict__ csr_eid,
    const float* __restrict__ no, const float* __restrict__ ni, const int* __restrict__ cnt_in,
    float* __restrict__ A48, int N){
  int v = blockIdx.x*4 + (threadIdx.x>>6);
  if(v >= N) return;
  int lane = threadIdx.x & 63;
  int beg = csr_off[v], end = csr_off[v+1];
  float acc = 0.f;
  for(int p=beg; p<end; p++){
    int s = csr_src[p]; int e = csr_eid[p];
    if(lane < 32)      acc += node_x[(size_t)s*32 + lane] * no[s];
    else if(lane < 48) acc += edge_e[(size_t)e*16 + (lane-32)];
  }
  int ci = cnt_in[v];
  float out;
  if(lane < 32)      out = acc * ni[v];
  else if(lane < 48) out = acc * (1.f/(float)max(ci,1));
  else if(lane == 48) out = (ci>0) ? 1.f : 0.f;
  else out = 0.f;
  A48[(size_t)v*64 + lane] = out;
}

// ---------------- per-layer gather -> single bf16 ----------------
__global__ __launch_bounds__(256) void k_gather_bf(const float* __restrict__ h,
   const int* __restrict__ csr_off, const int* __restrict__ csr_src,
   const float* __restrict__ no, const float* __restrict__ ni,
   unsigned short* __restrict__ ahi, int N, int Npad){
  int v = blockIdx.x*4 + (threadIdx.x>>6);
  if(v >= Npad) return;
  int lane = threadIdx.x & 63;
  float4 acc = make_float4(0.f,0.f,0.f,0.f);
  if(v < N){
    int beg = csr_off[v], end = csr_off[v+1];
    for(int p=beg; p<end; p++){
      int s = csr_src[p];
      float w = no[s];
      float4 x = *(const float4*)&h[(size_t)s*HDIM + lane*4];
      acc.x += x.x*w; acc.y += x.y*w; acc.z += x.z*w; acc.w += x.w*w;
    }
    float sc = ni[v];
    acc.x*=sc; acc.y*=sc; acc.z*=sc; acc.w*=sc;
  }
  ushort4 hv = make_ushort4(f2bf(acc.x), f2bf(acc.y), f2bf(acc.z), f2bf(acc.w));
  *(ushort4*)&ahi[(size_t)v*HDIM + lane*4] = hv;
}

// ---------------- layer GEMM v4: A single-bf16 in LDS, lean row-parallel epilogue ----------------
// block = 256 thr = 4 waves; tile 64 rows x 256 cols; wave tile 64x64 (2x2 of 32x32)
// A (32KB) staged once (swizzled); 2-term MFMA (Ah*Bh + Ah*Bl); epilogue via 64KB LDS
// z-buffer (aliases A region) then row-parallel LN/FiLM/SiLU with float4 traffic.
template<bool LAST>
__global__ __launch_bounds__(256, 2) void k_layer_mfma(
    const unsigned short* __restrict__ Ahi,
    const unsigned short* __restrict__ Bhi, const unsigned short* __restrict__ Blo,
    const float* __restrict__ bias, const float* __restrict__ lng, const float* __restrict__ lnb,
    const float* __restrict__ gamL, const float* __restrict__ betL,
    const int* __restrict__ n_index, float* __restrict__ h,
    const float* __restrict__ hw, float* __restrict__ gsum, int N){
  __shared__ __align__(16) char smem[65536];   // stage: 32KB A; epilogue: 64KB z
  unsigned short* AsH = (unsigned short*)smem;
  float* zbuf = (float*)smem;
  const int tid = threadIdx.x;
  const int w = tid >> 6, l = tid & 63;
  const int half = l >> 5, lcol = l & 31;
  const int row0 = blockIdx.x * 64;
  const int colb = w * 64;

  const size_t bb = (size_t)(colb + lcol)*HDIM + half*8;

  // B prefetch: 4 rotating slots, issue 3 ahead
  short8v Bh0[4], Bh1[4], Bl0[4], Bl1[4];
  #define LOADB(t, s) { \
    Bh0[s] = *(const short8v*)&Bhi[bb + (t)*16]; \
    Bh1[s] = *(const short8v*)&Bhi[bb + 32*HDIM + (t)*16]; \
    Bl0[s] = *(const short8v*)&Blo[bb + (t)*16]; \
    Bl1[s] = *(const short8v*)&Blo[bb + 32*HDIM + (t)*16]; }
  LOADB(0,0) LOADB(1,1) LOADB(2,2)

  // stage entire A tile (bf16 hi only): 8 chunks x (64 lanes*16B)
  {
    const int m = tid & 31;          // 16B slot within row
    const int rofs = tid >> 5;       // 0..7
    #pragma unroll
    for(int chunk=0; chunk<8; chunk++){
      const int row = chunk*8 + rofs;
      const int msw = (m & 24) | ((m ^ row) & 7);           // inverse-swizzled source slot
      const size_t src = (size_t)(row0 + row)*HDIM + msw*8;
      gload_lds16(&Ahi[src], (char*)smem + chunk*4096 + tid*16);
    }
  }
  __syncthreads();   // all A staged

  f32x16 acc[2][2] = {};
  const char* baseH = (const char*)smem;

  #pragma unroll
  for(int t=0; t<16; t++){
    if(t < 13) LOADB(t+3, (t+3)&3)
    const int s = t & 3;
    const int g = t*2 + half;                         // global 16B slot in row
    const int slot = (g & 24) | ((g ^ lcol) & 7);     // swizzled LDS slot
    short8v ah0 = *(const short8v*)(baseH + lcol*512 + slot*16);
    short8v ah1 = *(const short8v*)(baseH + (32+lcol)*512 + slot*16);

    acc[0][0] = __builtin_amdgcn_mfma_f32_32x32x16_bf16(ah0, Bh0[s], acc[0][0], 0,0,0);
    acc[0][1] = __builtin_amdgcn_mfma_f32_32x32x16_bf16(ah0, Bh1[s], acc[0][1], 0,0,0);
    acc[1][0] = __builtin_amdgcn_mfma_f32_32x32x16_bf16(ah1, Bh0[s], acc[1][0], 0,0,0);
    acc[1][1] = __builtin_amdgcn_mfma_f32_32x32x16_bf16(ah1, Bh1[s], acc[1][1], 0,0,0);
    acc[0][0] = __builtin_amdgcn_mfma_f32_32x32x16_bf16(ah0, Bl0[s], acc[0][0], 0,0,0);
    acc[0][1] = __builtin_amdgcn_mfma_f32_32x32x16_bf16(ah0, Bl1[s], acc[0][1], 0,0,0);
    acc[1][0] = __builtin_amdgcn_mfma_f32_32x32x16_bf16(ah1, Bl0[s], acc[1][0], 0,0,0);
    acc[1][1] = __builtin_amdgcn_mfma_f32_32x32x16_bf16(ah1, Bl1[s], acc[1][1], 0,0,0);
  }
  #undef LOADB

  // ---- epilogue phase 1: z = acc + bias  ->  LDS zbuf[64][256] (f32) ----
  float bias_c[2];
  bias_c[0] = bias[colb + lcol];
  bias_c[1] = bias[colb + 32 + lcol];
  __syncthreads();   // all waves done reading A from LDS
  #pragma unroll
  for(int mt=0; mt<2; mt++){
    #pragma unroll
    for(int r=0; r<16; r++){
      const int rl = (r&3) + 8*(r>>2) + 4*half;
      const int row = mt*32 + rl;
      zbuf[row*HDIM + colb      + lcol] = acc[mt][0][r] + bias_c[0];
      zbuf[row*HDIM + colb + 32 + lcol] = acc[mt][1][r] + bias_c[1];
    }
  }
  __syncthreads();

  // ---- epilogue phase 2: row-parallel LN/FiLM/SiLU (+residual or head dot) ----
  // wave w owns rows w*16 .. w*16+15; 64 lanes hold the 256-col row as float4.
  const float4 lng4 = *(const float4*)&lng[l*4];
  const float4 lnb4 = *(const float4*)&lnb[l*4];
  float4 hw4;
  if(LAST) hw4 = *(const float4*)&hw[l*4];
  #pragma unroll
  for(int rr=0; rr<16; rr++){
    const int row = w*16 + rr;
    const int grow = row0 + row;
    const bool ok = grow < N;
    float4 z4 = *(const float4*)&zbuf[row*HDIM + l*4];
    float s = z4.x + z4.y + z4.z + z4.w;
    float q = z4.x*z4.x + z4.y*z4.y + z4.z*z4.z + z4.w*z4.w;
    #pragma unroll
    for(int off=1; off<64; off<<=1){ s += __shfl_xor(s, off, 64); q += __shfl_xor(q, off, 64); }
    const float mu = s * (1.f/256.f);
    const float rs = rsqrtf(fmaxf(q*(1.f/256.f) - mu*mu, 0.f) + 1e-5f);
    const int bidx = ok ? n_index[grow] : 0;
    const float4 gam4 = *(const float4*)&gamL[(size_t)bidx*HDIM + l*4];
    const float4 bet4 = *(const float4*)&betL[(size_t)bidx*HDIM + l*4];
    float4 o;
    { float zn=(z4.x-mu)*rs*lng4.x+lnb4.x; o.x=silu_(zn*(1.f+gam4.x)+bet4.x); }
    { float zn=(z4.y-mu)*rs*lng4.y+lnb4.y; o.y=silu_(zn*(1.f+gam4.y)+bet4.y); }
    { float zn=(z4.z-mu)*rs*lng4.z+lnb4.z; o.z=silu_(zn*(1.f+gam4.z)+bet4.z); }
    { float zn=(z4.w-mu)*rs*lng4.w+lnb4.w; o.w=silu_(zn*(1.f+gam4.w)+bet4.w); }
    if(LAST){
      float4 hv = ok ? *(const float4*)&h[(size_t)grow*HDIM + l*4]
                     : make_float4(0.f,0.f,0.f,0.f);
      float rd = (o.x+hv.x)*hw4.x + (o.y+hv.y)*hw4.y + (o.z+hv.z)*hw4.z + (o.w+hv.w)*hw4.w;
      #pragma unroll
      for(int off=1; off<64; off<<=1) rd += __shfl_xor(rd, off, 64);
      if(l == 0 && ok) atomicAdd(&gsum[bidx], rd);
    } else {
      if(ok){
        float4 hv = *(const float4*)&h[(size_t)grow*HDIM + l*4];
        o.x += hv.x; o.y += hv.y; o.z += hv.z; o.w += hv.w;
        *(float4*)&h[(size_t)grow*HDIM + l*4] = o;
      }
    }
  }
}

__global__ void k_final(const float* __restrict__ gsum, const int* __restrict__ gcnt,
                        const float* __restrict__ hb, float* __restrict__ out, int B){
  int b = blockIdx.x*256 + threadIdx.x;
  if(b < B) out[b] = gsum[b] / (float)max(gcnt[b],1) + hb[0];
}

extern "C" void kernel_launch(void* const* d_in, const int* in_sizes, int n_in,
                              void* d_out, int out_size, void* d_ws, size_t ws_size,
                              hipStream_t stream){
  const float* node_x   = (const float*)d_in[0];
  const float* edge_e   = (const float*)d_in[1];
  const float* t        = (const float*)d_in[2];
  const int*   n_index  = (const int*)d_in[3];
  const int*   src      = (const int*)d_in[4];
  const int*   dst      = (const int*)d_in[5];
  const float* in_conv_w= (const float*)d_in[6];
  const float* in_conv_b= (const float*)d_in[7];
  const float* edge_w   = (const float*)d_in[8];
  const float* edge_b   = (const float*)d_in[9];
  const float* t_w1     = (const float*)d_in[10];
  const float* t_b1     = (const float*)d_in[11];
  const float* t_w2     = (const float*)d_in[12];
  const float* t_b2     = (const float*)d_in[13];
  const float* conv2_w  = (const float*)d_in[16];
  const float* conv2_b  = (const float*)d_in[17];
  const float* ln2_g    = (const float*)d_in[20];
  const float* ln2_b    = (const float*)d_in[21];
  const float* film2_w  = (const float*)d_in[24];
  const float* film2_b  = (const float*)d_in[25];
  const float* head_w   = (const float*)d_in[26];
  const float* head_b   = (const float*)d_in[27];

  const int N = in_sizes[3];
  const int E = in_sizes[4];
  const int B = in_sizes[2];
  const int Npad = (N + 63) & ~63;

  char* w = (char*)d_ws;
  auto alloc = [&](size_t bytes)->char*{
    char* p = w; w += (bytes + 255) & ~(size_t)255; return p;
  };
  int*   cnt_out = (int*)  alloc((size_t)N*4);
  int*   cnt_in  = (int*)  alloc((size_t)N*4);
  float* no      = (float*)alloc((size_t)N*4);
  float* ni      = (float*)alloc((size_t)N*4);
  int*   csr_off = (int*)  alloc((size_t)(N+1)*4);
  int*   csr_pos = (int*)  alloc((size_t)N*4);
  int*   csr_src = (int*)  alloc((size_t)E*4);
  int*   csr_eid = (int*)  alloc((size_t)E*4);
  int*   partial = (int*)  alloc((size_t)256*4);
  float* cond    = (float*)alloc((size_t)B*HDIM*4);
  float* gbX     = (float*)alloc((size_t)12*B*HDIM*4);
  float* gsum    = (float*)alloc((size_t)B*4);
  int*   gcnt    = (int*)  alloc((size_t)B*4);
  float* h       = (float*)alloc((size_t)N*HDIM*4);
  unsigned short* agg_hi = (unsigned short*)alloc((size_t)Npad*HDIM*2);
  unsigned short* Wthi   = (unsigned short*)alloc((size_t)NLAYERS*HDIM*HDIM*2);
  unsigned short* Wtlo   = (unsigned short*)alloc((size_t)NLAYERS*HDIM*HDIM*2);
  float* wcat    = (float*)alloc((size_t)64*HDIM*4);
  float* A48     = (float*)alloc((size_t)Npad*64*4);

  hipMemsetAsync(cnt_out, 0, (size_t)N*4, stream);
  hipMemsetAsync(cnt_in,  0, (size_t)N*4, stream);
  hipMemsetAsync(gsum,    0, (size_t)B*4, stream);
  hipMemsetAsync(gcnt,    0, (size_t)B*4, stream);

  int gE = (E+255)/256, gN = (N+255)/256;
  int nb1 = (N+1023)/1024;
  k_count<<<gE,256,0,stream>>>(src, dst, E, cnt_out, cnt_in);
  k_scan1<<<nb1,256,0,stream>>>(cnt_in, partial, N);
  k_scan2<<<1,256,0,stream>>>(partial, csr_off, nb1, N);
  k_scan3<<<nb1,256,0,stream>>>(cnt_in, partial, csr_off, N);
  k_prep<<<gN,256,0,stream>>>(cnt_out, cnt_in, csr_off, n_index, no, ni, csr_pos, gcnt, N);
  k_fill<<<gE,256,0,stream>>>(src, dst, E, csr_pos, csr_src, csr_eid);

  k_cond<<<B,256,0,stream>>>(t, t_w1, t_b1, t_w2, t_b2, cond);
  k_gemm_f32<256><<<dim3(B/64,12),256,0,stream>>>(cond, HDIM, film2_w, 512, film2_b,
                                                  gbX, HDIM, B, 1);

  k_w2b<<<NLAYERS*HDIM*HDIM/256,256,0,stream>>>(conv2_w, Wthi, Wtlo);
  k_wcat<<<64,256,0,stream>>>(in_conv_w, edge_w, edge_b, wcat);
  k_init_agg<<<(N+3)/4,256,0,stream>>>(node_x, edge_e, csr_off, csr_src, csr_eid,
                                       no, ni, cnt_in, A48, N);
  k_gemm_f32<64><<<Npad/64,256,0,stream>>>(A48, 64, wcat, HDIM, in_conv_b, h, HDIM, N, 0);

  for(int i=0;i<NLAYERS;i++){
    k_gather_bf<<<Npad/4,256,0,stream>>>(h, csr_off, csr_src, no, ni, agg_hi, N, Npad);
    if(i < NLAYERS-1)
      k_layer_mfma<false><<<Npad/64,256,0,stream>>>(agg_hi,
          Wthi + (size_t)i*HDIM*HDIM, Wtlo + (size_t)i*HDIM*HDIM,
          conv2_b + (size_t)i*HDIM,
          ln2_g + (size_t)i*HDIM, ln2_b + (size_t)i*HDIM,
          gbX + (size_t)(2*i)*B*HDIM, gbX + (size_t)(2*i+1)*B*HDIM,
          n_index, h, head_w, gsum, N);
    else
      k_layer_mfma<true><<<Npad/64,256,0,stream>>>(agg_hi,
          Wthi + (size_t)i*HDIM*HDIM, Wtlo + (size_t)i*HDIM*HDIM,
          conv2_b + (size_t)i*HDIM,
          ln2_g + (size_t)i*HDIM, ln2_b + (size_t)i*HDIM,
          gbX + (size_t)(2*i)*B*HDIM, gbX + (size_t)(2*i+1)*B*HDIM,
          n_index, h, head_w, gsum, N);
  }

  k_final<<<(B+255)/256,256,0,stream>>>(gsum, gcnt, head_b, (float*)d_out, B);
}